// Round 12
// baseline (581.871 us; speedup 1.0000x reference)
//
#include <hip/hip_runtime.h>
#include <cstdint>
#include <cstddef>

// ---------------------------------------------------------------------------
// JAX threefry2x32 (20 rounds). fold_in(key(42), i) = threefry((0,42),(0,i))
// partitionable 32-bit random_bits: bits = o0 ^ o1 (XOR-fold)   [validated r2]
// uniform: u = bitcast((bits>>9)|0x3f800000) - 1.0f ; keep iff u < 0.9f
// ---------------------------------------------------------------------------
__host__ __device__ inline void tf2x32(uint32_t k0, uint32_t k1,
                                       uint32_t x0, uint32_t x1,
                                       uint32_t* o0, uint32_t* o1)
{
    uint32_t ks2 = k0 ^ k1 ^ 0x1BD11BDAu;
    x0 += k0; x1 += k1;
#define TF_R(r) do { x0 += x1; x1 = (x1 << (r)) | (x1 >> (32 - (r))); x1 ^= x0; } while (0)
    TF_R(13); TF_R(15); TF_R(26); TF_R(6);
    x0 += k1;  x1 += ks2 + 1u;
    TF_R(17); TF_R(29); TF_R(16); TF_R(24);
    x0 += ks2; x1 += k0 + 2u;
    TF_R(13); TF_R(15); TF_R(26); TF_R(6);
    x0 += k0;  x1 += k1 + 3u;
    TF_R(17); TF_R(29); TF_R(16); TF_R(24);
    x0 += k1;  x1 += ks2 + 4u;
    TF_R(13); TF_R(15); TF_R(26); TF_R(6);
    x0 += ks2; x1 += k0 + 5u;
#undef TF_R
    *o0 = x0; *o1 = x1;
}

__device__ inline float drop_scale(uint32_t fk0, uint32_t fk1, uint32_t idx)
{
    uint32_t o0, o1;
    tf2x32(fk0, fk1, 0u, idx, &o0, &o1);
    uint32_t bits = o0 ^ o1;
    float u = __uint_as_float((bits >> 9) | 0x3f800000u) - 1.0f;
    return (u < 0.9f) ? (1.0f / 0.9f) : 0.0f;
}

// bf16 helpers (round-to-nearest-even)
__device__ inline ushort bf16_rn(float f)
{
    uint32_t u = __float_as_uint(f);
    u += 0x7fffu + ((u >> 16) & 1u);
    return (ushort)(u >> 16);
}
__device__ inline float bf16_f(ushort h) { return __uint_as_float(((uint32_t)h) << 16); }
__device__ inline uint32_t pack2bf(float a, float b)
{
    return (uint32_t)bf16_rn(a) | ((uint32_t)bf16_rn(b) << 16);
}
__device__ inline float bflo(uint32_t u) { return __uint_as_float(u << 16); }
__device__ inline float bfhi(uint32_t u) { return __uint_as_float(u & 0xffff0000u); }

typedef __attribute__((ext_vector_type(8))) short bf16x8;
typedef __attribute__((ext_vector_type(4))) float f32x4;

// ---------------------------------------------------------------------------
// features f32 -> packed bf16x2 (one-time per call, streaming)
// ---------------------------------------------------------------------------
__global__ __launch_bounds__(256) void fcvt_kernel(
    const float4* __restrict__ in, uint2* __restrict__ out, long long n4)
{
    long long stride = (long long)gridDim.x * 256;
    for (long long i = blockIdx.x * 256LL + threadIdx.x; i < n4; i += stride) {
        float4 v = in[i];
        out[i] = make_uint2(pack2bf(v.x, v.y), pack2bf(v.z, v.w));
    }
}

// ---------------------------------------------------------------------------
// prep_all: per type t (8 blocks):
//   1) convW[t] f32 [128k][128c] -> WThi/lo swizzled bf16 [c][swz(k)]
//   2) Wf[t] = convW[t] @ fcW  -> WfThi/lo swizzled bf16 directly (no f32 buf)
//   3) bfb[t] = convb[t] @ fcW + fcb
// ---------------------------------------------------------------------------
__global__ __launch_bounds__(256) void prep_all_kernel(
    const float* __restrict__ convW, const float* __restrict__ convb,
    const float* __restrict__ fcW, const float* __restrict__ fcb,
    ushort* __restrict__ WThi, ushort* __restrict__ WTlo,
    ushort* __restrict__ WfThi, ushort* __restrict__ WfTlo,
    float* __restrict__ bfb)
{
    __shared__ float F[128 * 64];
    int t = blockIdx.x, tid = threadIdx.x;
    #pragma unroll
    for (int it = 0; it < 8; ++it) {
        int idx4 = (it * 256 + tid) * 4;
        *(float4*)&F[idx4] = *(const float4*)&fcW[idx4];
    }
    __syncthreads();

    // 1) convW -> swizzled split-bf16 (C=128)
    {
        const float* S = convW + (size_t)t * 16384;
        ushort* DH = WThi + (size_t)t * 16384;
        ushort* DL = WTlo + (size_t)t * 16384;
        for (int idx = tid; idx < 16384; idx += 256) {
            int k = idx >> 7, c = idx & 127;
            float v = S[idx];
            ushort hi = bf16_rn(v);
            ushort lo = bf16_rn(v - bf16_f(hi));
            int pos = c * 128 + ((((k >> 3) ^ (c & 15)) << 3) | (k & 7));
            DH[pos] = hi; DL[pos] = lo;
        }
    }

    // 2) Wf row r = convW[t][r] @ F ; emit swizzled split-bf16 (C=64)
    {
        int r = tid >> 1, cb = (tid & 1) * 32;
        const float* Wrow = convW + (size_t)t * 16384 + (size_t)r * 128;
        float acc[32];
        #pragma unroll
        for (int c = 0; c < 32; ++c) acc[c] = 0.f;
        for (int k = 0; k < 128; ++k) {
            float w = Wrow[k];
            #pragma unroll
            for (int c = 0; c < 32; ++c) acc[c] += w * F[k * 64 + cb + c];
        }
        ushort* FH = WfThi + (size_t)t * 8192;
        ushort* FL = WfTlo + (size_t)t * 8192;
        int swzr = (r & 7);
        #pragma unroll
        for (int c = 0; c < 32; ++c) {
            int col = cb + c;
            float v = acc[c];
            ushort hi = bf16_rn(v);
            ushort lo = bf16_rn(v - bf16_f(hi));
            int pos = col * 128 + ((((r >> 3) ^ (col & 15)) << 3) | swzr);
            FH[pos] = hi; FL[pos] = lo;
        }
    }

    // 3) bfb
    if (tid < 64) {
        float a = fcb[tid];
        const float* bt = convb + (size_t)t * 128;
        for (int k = 0; k < 128; ++k) a += bt[k] * F[k * 64 + tid];
        bfb[(size_t)t * 64 + tid] = a;
    }
}

// ---------------------------------------------------------------------------
// Bucketed CSR build + type bucketing, merged kernels.
// Bucket = dst>>10. pairs entry: (dstLocal << 22) | src
// ---------------------------------------------------------------------------
#define EPB 4096

// hist_all: y<3 = per-layer bucket hist -> tot ; y==3 = type hist -> tcnt
__global__ __launch_bounds__(256) void hist_all_kernel(
    const int* __restrict__ d0, const int* __restrict__ d1, const int* __restrict__ d2,
    const int* __restrict__ t1, const int* __restrict__ t2, const int* __restrict__ t3,
    int E0, int E1, int E2, int N1, int N2, int N3,
    int nb0, int nb1, int nb2, int nblk0, int nblk1, int nblk2,
    uint32_t* __restrict__ tot, uint32_t* __restrict__ tcnt)
{
    int L = blockIdx.y;
    int tid = threadIdx.x;
    if (L < 3) {
        const int* dst = L == 0 ? d0 : (L == 1 ? d1 : d2);
        int E  = L == 0 ? E0 : (L == 1 ? E1 : E2);
        int NB = L == 0 ? nb0 : (L == 1 ? nb1 : nb2);
        int nblk = L == 0 ? nblk0 : (L == 1 ? nblk1 : nblk2);
        int gO = L == 0 ? 0 : (L == 1 ? nb0 : nb0 + nb1);
        if ((int)blockIdx.x >= nblk) return;
        __shared__ uint32_t lh[256];
        lh[tid] = 0;
        __syncthreads();
        int base = blockIdx.x * EPB;
        for (int i = tid; i < EPB; i += 256) {
            int e = base + i;
            if (e < E) atomicAdd(&lh[((uint32_t)dst[e]) >> 10], 1u);
        }
        __syncthreads();
        if (tid < NB && lh[tid]) atomicAdd(&tot[gO + tid], lh[tid]);
    } else {
        int totalN = N1 + N2 + N3;
        if ((int)blockIdx.x * 256 >= totalN) return;
        __shared__ uint32_t lh[24];
        if (tid < 24) lh[tid] = 0;
        __syncthreads();
        int i = blockIdx.x * 256 + tid;
        if (i < N1) atomicAdd(&lh[t1[i]], 1u);
        else if (i < N1 + N2) atomicAdd(&lh[8 + t2[i - N1]], 1u);
        else if (i < totalN) atomicAdd(&lh[16 + t3[i - N1 - N2]], 1u);
        __syncthreads();
        if (tid < 24 && lh[tid]) atomicAdd(&tcnt[tid], lh[tid]);
    }
}

// scan_all: bucket scans (bo, bcur, rowptr sentinels) + type scans
// (boff padded, tcur, order3 pad fill). One block, 512 threads.
__global__ __launch_bounds__(512) void scan_all_kernel(
    const uint32_t* __restrict__ tot, uint32_t* __restrict__ bo,
    uint32_t* __restrict__ bcur, uint32_t* __restrict__ rowptr3,
    const uint32_t* __restrict__ tcnt, int* __restrict__ boff,
    uint32_t* __restrict__ tcur, int* __restrict__ order3,
    int nb0, int nb1, int nb2, int N1, int N2, int N3,
    int r1, int r2, int no1p, int no2p)
{
    __shared__ uint32_t bol[348];
    __shared__ int pB[27];
    __shared__ int cnts[24];
    int t = threadIdx.x;
    int TB = nb0 + nb1 + nb2;
    if (t < 3) {
        int nb = t == 0 ? nb0 : (t == 1 ? nb1 : nb2);
        int g0 = t == 0 ? 0 : (t == 1 ? nb0 : nb0 + nb1);
        int gi0 = g0 + t;
        uint32_t run = 0;
        for (int i = 0; i < nb; ++i) { bol[gi0 + i] = run; run += tot[g0 + i]; }
        bol[gi0 + nb] = run;
        int rp = t == 0 ? 0 : (t == 1 ? r1 : r2);
        int N = t == 0 ? N1 : (t == 1 ? N2 : N3);
        rowptr3[rp + N] = run;
    }
    if (t == 3) {
        for (int L = 0; L < 3; ++L) {
            int a = 0;
            for (int ty = 0; ty < 8; ++ty) {
                pB[L * 9 + ty] = a;
                int c = (int)tcnt[L * 8 + ty];
                cnts[L * 8 + ty] = c;
                tcur[L * 8 + ty] = (uint32_t)a;
                a += (c + 127) & ~127;
            }
            pB[L * 9 + 8] = a;
        }
    }
    __syncthreads();
    for (int i = t; i < TB + 3; i += 512) bo[i] = bol[i];
    if (t < TB) {
        int layer = t < nb0 ? 0 : (t < nb0 + nb1 ? 1 : 2);
        bcur[t] = bol[t + layer];
    }
    if (t < 27) boff[t] = pB[t];
    if (t < 24) {
        int L = t >> 3, ty = t & 7;
        int noff = L == 0 ? 0 : (L == 1 ? no1p : no2p);
        int s = pB[L * 9 + ty] + cnts[t];
        int e2 = pB[L * 9 + ty + 1];
        for (int k = s; k < e2; ++k) order3[noff + k] = -1;
    }
}

// scatter_all: y<3 = edge scatter into pairs ; y==3 = order3 fill
__global__ __launch_bounds__(256) void scatter_all_kernel(
    const int* __restrict__ s0, const int* __restrict__ d0,
    const int* __restrict__ s1, const int* __restrict__ d1,
    const int* __restrict__ s2, const int* __restrict__ d2,
    const int* __restrict__ t1, const int* __restrict__ t2, const int* __restrict__ t3,
    int E0, int E1, int E2, int N1, int N2, int N3,
    int nb0, int nb1, int nb2, int nblk0, int nblk1, int nblk2,
    uint32_t* __restrict__ bcur, uint32_t* __restrict__ pairs,
    uint32_t* __restrict__ tcur, int* __restrict__ order3, int no1p, int no2p)
{
    int L = blockIdx.y;
    int tid = threadIdx.x;
    if (L < 3) {
        const int* src = L == 0 ? s0 : (L == 1 ? s1 : s2);
        const int* dst = L == 0 ? d0 : (L == 1 ? d1 : d2);
        int E  = L == 0 ? E0 : (L == 1 ? E1 : E2);
        int NB = L == 0 ? nb0 : (L == 1 ? nb1 : nb2);
        int nblk = L == 0 ? nblk0 : (L == 1 ? nblk1 : nblk2);
        int gO = L == 0 ? 0 : (L == 1 ? nb0 : nb0 + nb1);
        uint32_t* pr = pairs + (L == 0 ? 0 : (L == 1 ? E0 : E0 + E1));
        if ((int)blockIdx.x >= nblk) return;

        __shared__ uint32_t lh[256], lbase[256], rank[256];
        lh[tid] = 0; rank[tid] = 0;
        __syncthreads();
        int base = blockIdx.x * EPB;
        for (int i = tid; i < EPB; i += 256) {
            int e = base + i;
            if (e < E) atomicAdd(&lh[((uint32_t)dst[e]) >> 10], 1u);
        }
        __syncthreads();
        if (tid < NB && lh[tid]) lbase[tid] = atomicAdd(&bcur[gO + tid], lh[tid]);
        __syncthreads();
        for (int i = tid; i < EPB; i += 256) {
            int e = base + i;
            if (e < E) {
                uint32_t d = (uint32_t)dst[e];
                uint32_t bk = d >> 10;
                uint32_t r = atomicAdd(&rank[bk], 1u);
                pr[lbase[bk] + r] = ((d & 1023u) << 22) | (uint32_t)src[e];
            }
        }
    } else {
        int totalN = N1 + N2 + N3;
        if ((int)blockIdx.x * 256 >= totalN) return;
        __shared__ uint32_t lh[24], lbase[24];
        if (tid < 24) lh[tid] = 0;
        __syncthreads();
        int i = blockIdx.x * 256 + tid;
        int slot = -1, idx = 0; uint32_t r = 0;
        if (i < N1) { idx = i; slot = t1[idx]; }
        else if (i < N1 + N2) { idx = i - N1; slot = 8 + t2[idx]; }
        else if (i < totalN) { idx = i - N1 - N2; slot = 16 + t3[idx]; }
        if (slot >= 0) r = atomicAdd(&lh[slot], 1u);
        __syncthreads();
        if (tid < 24 && lh[tid]) lbase[tid] = atomicAdd(&tcur[tid], lh[tid]);
        __syncthreads();
        if (slot >= 0) {
            int noff = slot < 8 ? 0 : (slot < 16 ? no1p : no2p);
            order3[noff + lbase[slot] + r] = idx;
        }
    }
}

// bfill: one block per bucket: LDS hist -> scan -> rowptr + fine elist fill
__global__ __launch_bounds__(256) void bfill_kernel(
    const uint32_t* __restrict__ bo, const uint32_t* __restrict__ pairs,
    int* __restrict__ elist3, uint32_t* __restrict__ rowptr3,
    int nb0, int nb1, int nb2, int N1, int N2, int N3,
    int E0, int E1, int r1, int r2)
{
    __shared__ uint32_t hist[1024];
    __shared__ uint32_t cur[1024];
    __shared__ uint32_t psum[256];
    int g = blockIdx.x, tid = threadIdx.x;
    int layer, lb, N, Eoff, rp;
    if (g < nb0) { layer = 0; lb = g; N = N1; Eoff = 0; rp = 0; }
    else if (g < nb0 + nb1) { layer = 1; lb = g - nb0; N = N2; Eoff = E0; rp = r1; }
    else { layer = 2; lb = g - nb0 - nb1; N = N3; Eoff = E0 + E1; rp = r2; }
    uint32_t off = bo[g + layer], end = bo[g + layer + 1];
    int nodeBase = lb << 10;
    int nodesIn = N - nodeBase; if (nodesIn > 1024) nodesIn = 1024;

    #pragma unroll
    for (int i = 0; i < 4; ++i) hist[tid * 4 + i] = 0;
    __syncthreads();
    for (uint32_t e = off + tid; e < end; e += 256)
        atomicAdd(&hist[pairs[Eoff + e] >> 22], 1u);
    __syncthreads();

    uint32_t x[4]; uint32_t s = 0;
    #pragma unroll
    for (int i = 0; i < 4; ++i) { x[i] = hist[tid * 4 + i]; s += x[i]; }
    psum[tid] = s; __syncthreads();
    uint32_t inc = s;
    #pragma unroll
    for (int o = 1; o < 256; o <<= 1) {
        uint32_t y = (tid >= o) ? psum[tid - o] : 0u;
        __syncthreads();
        inc += y; psum[tid] = inc;
        __syncthreads();
    }
    uint32_t run = off + inc - s;
    #pragma unroll
    for (int i = 0; i < 4; ++i) { cur[tid * 4 + i] = run; run += x[i]; }
    __syncthreads();

    for (int i = tid; i < nodesIn; i += 256)
        rowptr3[rp + nodeBase + i] = cur[i];
    __syncthreads();

    for (uint32_t e = off + tid; e < end; e += 256) {
        uint32_t pk = pairs[Eoff + e];
        uint32_t pos = atomicAdd(&cur[pk >> 22], 1u);
        elist3[Eoff + pos] = (int)(pk & 0x3FFFFFu);
    }
}

// ---------------------------------------------------------------------------
// Gather-aggregate: 2 nodes per wave; 8+8 main loop with INDEX PREFETCH
// (next batch's elist loads issue while current gathers are in flight).
// ---------------------------------------------------------------------------
__global__ __launch_bounds__(256) void aggregate_kernel(
    const uint32_t* __restrict__ hbf, const uint32_t* __restrict__ rowptr,
    const int* __restrict__ elist, uint32_t* __restrict__ agghi,
    uint32_t* __restrict__ agglo, int nout)
{
    int wid = threadIdx.x >> 6, lane = threadIdx.x & 63;
    int n0 = blockIdx.x * 8 + wid * 2;
    if (n0 >= nout) return;
    int n1 = n0 + 1;
    bool v1 = (n1 < nout);
    uint32_t b0 = rowptr[n0], e0 = rowptr[n0 + 1];
    uint32_t b1 = v1 ? rowptr[n1] : 0u, e1 = v1 ? rowptr[n1 + 1] : 0u;
    const uint32_t* base = hbf + lane;
    float a0x = 0.f, a0y = 0.f, a1x = 0.f, a1y = 0.f;
    uint32_t i0 = b0, i1 = b1;

    if (i0 + 8 <= e0 && i1 + 8 <= e1) {
        int ia[8], ib[8];
        #pragma unroll
        for (int k = 0; k < 8; ++k) { ia[k] = elist[i0 + k]; ib[k] = elist[i1 + k]; }
        for (;;) {
            uint32_t u[8], w[8];
            #pragma unroll
            for (int k = 0; k < 8; ++k) u[k] = base[(size_t)ia[k] * 64];
            #pragma unroll
            for (int k = 0; k < 8; ++k) w[k] = base[(size_t)ib[k] * 64];
            i0 += 8; i1 += 8;
            bool more = (i0 + 8 <= e0 && i1 + 8 <= e1);
            if (more) {
                #pragma unroll
                for (int k = 0; k < 8; ++k) { ia[k] = elist[i0 + k]; ib[k] = elist[i1 + k]; }
            }
            #pragma unroll
            for (int k = 0; k < 8; ++k) { a0x += bflo(u[k]); a0y += bfhi(u[k]); }
            #pragma unroll
            for (int k = 0; k < 8; ++k) { a1x += bflo(w[k]); a1y += bfhi(w[k]); }
            if (!more) break;
        }
    }
    while (i0 + 4 <= e0 && i1 + 4 <= e1) {
        uint32_t u[4], w[4];
        #pragma unroll
        for (int k = 0; k < 4; ++k) u[k] = base[(size_t)elist[i0 + k] * 64];
        #pragma unroll
        for (int k = 0; k < 4; ++k) w[k] = base[(size_t)elist[i1 + k] * 64];
        #pragma unroll
        for (int k = 0; k < 4; ++k) { a0x += bflo(u[k]); a0y += bfhi(u[k]); }
        #pragma unroll
        for (int k = 0; k < 4; ++k) { a1x += bflo(w[k]); a1y += bfhi(w[k]); }
        i0 += 4; i1 += 4;
    }
    while (i0 + 4 <= e0) {
        uint32_t u[4];
        #pragma unroll
        for (int k = 0; k < 4; ++k) u[k] = base[(size_t)elist[i0 + k] * 64];
        #pragma unroll
        for (int k = 0; k < 4; ++k) { a0x += bflo(u[k]); a0y += bfhi(u[k]); }
        i0 += 4;
    }
    while (i1 + 4 <= e1) {
        uint32_t w[4];
        #pragma unroll
        for (int k = 0; k < 4; ++k) w[k] = base[(size_t)elist[i1 + k] * 64];
        #pragma unroll
        for (int k = 0; k < 4; ++k) { a1x += bflo(w[k]); a1y += bfhi(w[k]); }
        i1 += 4;
    }
    for (; i0 < e0; ++i0) {
        uint32_t u = base[(size_t)elist[i0] * 64];
        a0x += bflo(u); a0y += bfhi(u);
    }
    for (; i1 < e1; ++i1) {
        uint32_t w = base[(size_t)elist[i1] * 64];
        a1x += bflo(w); a1y += bfhi(w);
    }

    float sc0 = 1.0f / fmaxf((float)(e0 - b0), 1.0f);
    a0x *= sc0; a0y *= sc0;
    ushort hx = bf16_rn(a0x); ushort lx = bf16_rn(a0x - bf16_f(hx));
    ushort hy = bf16_rn(a0y); ushort ly = bf16_rn(a0y - bf16_f(hy));
    agghi[(size_t)n0 * 64 + lane] = (uint32_t)hx | ((uint32_t)hy << 16);
    agglo[(size_t)n0 * 64 + lane] = (uint32_t)lx | ((uint32_t)ly << 16);
    if (v1) {
        float sc1 = 1.0f / fmaxf((float)(e1 - b1), 1.0f);
        a1x *= sc1; a1y *= sc1;
        ushort hx1 = bf16_rn(a1x); ushort lx1 = bf16_rn(a1x - bf16_f(hx1));
        ushort hy1 = bf16_rn(a1y); ushort ly1 = bf16_rn(a1y - bf16_f(hy1));
        agghi[(size_t)n1 * 64 + lane] = (uint32_t)hx1 | ((uint32_t)hy1 << 16);
        agglo[(size_t)n1 * 64 + lane] = (uint32_t)lx1 | ((uint32_t)ly1 << 16);
    }
}

// ---------------------------------------------------------------------------
// MFMA GEMM (split-bf16): out[n] = [relu](agg[n] @ W[t] + b[t]) [* dropout]
// A fragments direct from global; W staged in LDS (64.5KB, 4 waves/SIMD).
// ---------------------------------------------------------------------------
template<int DOUT, bool RELU, bool DROP, bool OUTBF>
__global__ __launch_bounds__(512) void mfma_gemm_kernel(
    const uint32_t* __restrict__ agghi, const uint32_t* __restrict__ agglo,
    const int* __restrict__ order, const int* __restrict__ off,
    const ushort* __restrict__ WThi, const ushort* __restrict__ WTlo,
    const float* __restrict__ bias8, void* __restrict__ houtv,
    uint32_t fk0, uint32_t fk1)
{
    __shared__ ushort WH[DOUT * 128];
    __shared__ ushort WL[DOUT * 128];
    __shared__ int ND[128];

    int b0 = blockIdx.x * 128;
    if (b0 >= off[8]) return;
    int t = 0;
    #pragma unroll
    for (int u = 1; u < 8; ++u) if (b0 >= off[u]) ++t;
    int tid = threadIdx.x;

    if (tid < 128) ND[tid] = order[b0 + tid];

    {
        const float4* sh = (const float4*)(WThi + (size_t)t * DOUT * 128);
        const float4* sl = (const float4*)(WTlo + (size_t)t * DOUT * 128);
        float4* dh = (float4*)WH; float4* dl = (float4*)WL;
        #pragma unroll
        for (int it = 0; it < DOUT * 16 / 512; ++it) {
            int c = it * 512 + tid;
            dh[c] = sh[c]; dl[c] = sl[c];
        }
    }
    __syncthreads();

    int wid = tid >> 6, lane = tid & 63;
    int r15 = lane & 15, q = lane >> 4;
    int arow = wid * 16 + r15;
    int nd_a = ND[arow];

    const bf16x8* gh = (const bf16x8*)agghi;
    const bf16x8* gl = (const bf16x8*)agglo;
    bf16x8 zero8 = (bf16x8){0, 0, 0, 0, 0, 0, 0, 0};
    bf16x8 ahv[4], alv[4];
    {
        size_t rowb = (size_t)(nd_a < 0 ? 0 : nd_a) * 16;
        #pragma unroll
        for (int ks = 0; ks < 4; ++ks) {
            size_t ix = rowb + (q + ks * 4);
            ahv[ks] = (nd_a >= 0) ? gh[ix] : zero8;
            alv[ks] = (nd_a >= 0) ? gl[ix] : zero8;
        }
    }

    constexpr int NF = DOUT / 16;
    f32x4 acc[NF];
    #pragma unroll
    for (int i = 0; i < NF; ++i) acc[i] = (f32x4){0.f, 0.f, 0.f, 0.f};

    const bf16x8* WHp = (const bf16x8*)WH;
    const bf16x8* WLp = (const bf16x8*)WL;

    #pragma unroll
    for (int ks = 0; ks < 4; ++ks) {
        int sch = (q + ks * 4) ^ r15;
        bf16x8 ah = ahv[ks];
        bf16x8 al = alv[ks];
        #pragma unroll
        for (int nf = 0; nf < NF; ++nf) {
            int col = nf * 16 + r15;
            bf16x8 bh = WHp[col * 16 + sch];
            bf16x8 bl = WLp[col * 16 + sch];
            acc[nf] = __builtin_amdgcn_mfma_f32_16x16x32_bf16(ah, bh, acc[nf], 0, 0, 0);
            acc[nf] = __builtin_amdgcn_mfma_f32_16x16x32_bf16(ah, bl, acc[nf], 0, 0, 0);
            acc[nf] = __builtin_amdgcn_mfma_f32_16x16x32_bf16(al, bh, acc[nf], 0, 0, 0);
        }
    }

    int ndr[4];
    #pragma unroll
    for (int r = 0; r < 4; ++r) ndr[r] = ND[wid * 16 + q * 4 + r];
    const float* bptr = bias8 + (size_t)t * DOUT;

    #pragma unroll
    for (int nf = 0; nf < NF; ++nf) {
        int col = nf * 16 + r15;
        float bv = bptr[col];
        float vr[4];
        #pragma unroll
        for (int r = 0; r < 4; ++r) {
            float v = acc[nf][r] + bv;
            if (RELU) v = fmaxf(v, 0.f);
            if (DROP) {
                int nd = ndr[r] < 0 ? 0 : ndr[r];
                v *= drop_scale(fk0, fk1, (uint32_t)nd * 128u + (uint32_t)col);
            }
            vr[r] = v;
        }
        if (OUTBF) {
            uint32_t* hb = (uint32_t*)houtv;
            #pragma unroll
            for (int r = 0; r < 4; ++r) {
                float w = __shfl_xor(vr[r], 1, 64);
                if ((lane & 1) == 0 && ndr[r] >= 0)
                    hb[(size_t)ndr[r] * (DOUT / 2) + (col >> 1)] = pack2bf(vr[r], w);
            }
        } else {
            float* ho = (float*)houtv;
            #pragma unroll
            for (int r = 0; r < 4; ++r)
                if (ndr[r] >= 0) ho[(size_t)ndr[r] * DOUT + col] = vr[r];
        }
    }
}

// ---------------------------------------------------------------------------
extern "C" void kernel_launch(void* const* d_in, const int* in_sizes, int n_in,
                              void* d_out, int out_size, void* d_ws, size_t ws_size,
                              hipStream_t stream)
{
    const float* features = (const float*)d_in[0];
    const int*   src0 = (const int*)d_in[1];
    const int*   dst0 = (const int*)d_in[2];
    const int*   types1 = (const int*)d_in[3];
    const int*   src1 = (const int*)d_in[4];
    const int*   dst1 = (const int*)d_in[5];
    const int*   types2 = (const int*)d_in[6];
    const int*   src2 = (const int*)d_in[7];
    const int*   dst2 = (const int*)d_in[8];
    const int*   types3 = (const int*)d_in[9];
    const float* convW = (const float*)d_in[10];
    const float* convb = (const float*)d_in[11];
    const float* fcW   = (const float*)d_in[12];
    const float* fcb   = (const float*)d_in[13];

    int N0 = in_sizes[0] / 128;
    int E0 = in_sizes[1], N1 = in_sizes[3];
    int E1 = in_sizes[4], N2 = in_sizes[6];
    int E2 = in_sizes[7], N3 = in_sizes[9];
    int totalN = N1 + N2 + N3;
    int totalE = E0 + E1 + E2;
    int r1 = N1 + 1, r2 = N1 + 1 + N2 + 1;
    int no1p = N1 + 1024, no2p = no1p + N2 + 1024;
    int maxN = N1 > N2 ? N1 : N2; if (N3 > maxN) maxN = N3;

    int nb0 = (N1 + 1023) >> 10, nb1 = (N2 + 1023) >> 10, nb2 = (N3 + 1023) >> 10;
    int TB = nb0 + nb1 + nb2;
    int nblk0 = (E0 + EPB - 1) / EPB, nblk1 = (E1 + EPB - 1) / EPB, nblk2 = (E2 + EPB - 1) / EPB;
    int nblkMax = nblk0 > nblk1 ? nblk0 : nblk1; if (nblk2 > nblkMax) nblkMax = nblk2;
    int nblkT = (totalN + 255) / 256;
    int gx = nblkMax > nblkT ? nblkMax : nblkT;

    char* ws = (char*)d_ws;
    size_t woff = 0;
    auto alloc = [&](size_t bytes) -> void* {
        void* p = ws + woff;
        woff = (woff + bytes + 255) & ~(size_t)255;
        return p;
    };
    uint32_t* fbf     = (uint32_t*)alloc((size_t)N0 * 64 * 4);
    uint32_t* hbf     = fbf;                       // alias: h after L0 agg done
    uint32_t* aggHi   = (uint32_t*)alloc((size_t)maxN * 64 * 4);
    uint32_t* pairs   = aggHi;                     // alias: dead before agg
    uint32_t* aggLo   = (uint32_t*)alloc((size_t)maxN * 64 * 4);
    uint32_t* rowptr3 = (uint32_t*)alloc((size_t)(totalN + 3) * 4);
    int*      elist3  = (int*)alloc((size_t)totalE * 4);
    int*      order3  = (int*)alloc((size_t)(totalN + 3 * 1024) * 4);
    uint32_t* tot     = (uint32_t*)alloc((size_t)(TB + 8 + 24) * 4);  // tot | tcnt
    uint32_t* tcnt    = tot + TB + 8;
    uint32_t* bcur    = (uint32_t*)alloc((size_t)(TB + 8) * 4);
    uint32_t* bo      = (uint32_t*)alloc((size_t)(TB + 3) * 4);
    int*      boff    = (int*)alloc(27 * 4);
    uint32_t* tcur    = (uint32_t*)alloc(24 * 4);
    float*    bfb     = (float*)alloc((size_t)8 * 64 * 4);
    ushort*   WThi    = (ushort*)alloc((size_t)8 * 128 * 128 * 2);
    ushort*   WTlo    = (ushort*)alloc((size_t)8 * 128 * 128 * 2);
    ushort*   WfThi   = (ushort*)alloc((size_t)8 * 64 * 128 * 2);
    ushort*   WfTlo   = (ushort*)alloc((size_t)8 * 64 * 128 * 2);
    (void)ws_size; (void)n_in; (void)out_size;

    // --- prep (2 dispatches) ---
    fcvt_kernel<<<4096, 256, 0, stream>>>(
        (const float4*)features, (uint2*)fbf, (long long)N0 * 32);
    prep_all_kernel<<<8, 256, 0, stream>>>(
        convW, convb, fcW, fcb, WThi, WTlo, WfThi, WfTlo, bfb);

    // --- CSR + type bucketing (5 dispatches) ---
    hipMemsetAsync(tot, 0, (size_t)(TB + 8 + 24) * 4, stream);
    hist_all_kernel<<<dim3(gx, 4), 256, 0, stream>>>(
        dst0, dst1, dst2, types1, types2, types3,
        E0, E1, E2, N1, N2, N3, nb0, nb1, nb2, nblk0, nblk1, nblk2, tot, tcnt);
    scan_all_kernel<<<1, 512, 0, stream>>>(
        tot, bo, bcur, rowptr3, tcnt, boff, tcur, order3,
        nb0, nb1, nb2, N1, N2, N3, r1, r2, no1p, no2p);
    scatter_all_kernel<<<dim3(gx, 4), 256, 0, stream>>>(
        src0, dst0, src1, dst1, src2, dst2, types1, types2, types3,
        E0, E1, E2, N1, N2, N3, nb0, nb1, nb2, nblk0, nblk1, nblk2,
        bcur, pairs, tcur, order3, no1p, no2p);
    bfill_kernel<<<TB, 256, 0, stream>>>(bo, pairs, elist3, rowptr3,
        nb0, nb1, nb2, N1, N2, N3, E0, E1, r1, r2);

    // fold-in keys
    uint32_t fk1a, fk1b, fk2a, fk2b;
    tf2x32(0u, 42u, 0u, 1u, &fk1a, &fk1b);
    tf2x32(0u, 42u, 0u, 2u, &fk2a, &fk2b);

    // --- layer 0 ---
    aggregate_kernel<<<(N1 + 7) / 8, 256, 0, stream>>>(
        fbf, rowptr3, elist3, aggHi, aggLo, N1);
    mfma_gemm_kernel<128, true, true, true><<<(N1 + 127) / 128 + 8, 512, 0, stream>>>(
        aggHi, aggLo, order3, boff, WThi, WTlo, convb, hbf, fk1a, fk1b);

    // --- layer 1 ---
    aggregate_kernel<<<(N2 + 7) / 8, 256, 0, stream>>>(
        hbf, rowptr3 + r1, elist3 + E0, aggHi, aggLo, N2);
    mfma_gemm_kernel<128, true, true, true><<<(N2 + 127) / 128 + 8, 512, 0, stream>>>(
        aggHi, aggLo, order3 + no1p, boff + 9, WThi, WTlo, convb, hbf, fk2a, fk2b);

    // --- layer 2 (fc folded, f32 out) ---
    aggregate_kernel<<<(N3 + 7) / 8, 256, 0, stream>>>(
        hbf, rowptr3 + r2, elist3 + E0 + E1, aggHi, aggLo, N3);
    mfma_gemm_kernel<64, false, false, false><<<(N3 + 127) / 128 + 8, 512, 0, stream>>>(
        aggHi, aggLo, order3 + no2p, boff + 18, WfThi, WfTlo, bfb, d_out, 0u, 0u);
}

// Round 13
// 538.510 us; speedup vs baseline: 1.0805x; 1.0805x over previous
//
#include <hip/hip_runtime.h>
#include <cstdint>
#include <cstddef>

// ---------------------------------------------------------------------------
// JAX threefry2x32 (20 rounds). fold_in(key(42), i) = threefry((0,42),(0,i))
// partitionable 32-bit random_bits: bits = o0 ^ o1 (XOR-fold)   [validated r2]
// uniform: u = bitcast((bits>>9)|0x3f800000) - 1.0f ; keep iff u < 0.9f
// ---------------------------------------------------------------------------
__host__ __device__ inline void tf2x32(uint32_t k0, uint32_t k1,
                                       uint32_t x0, uint32_t x1,
                                       uint32_t* o0, uint32_t* o1)
{
    uint32_t ks2 = k0 ^ k1 ^ 0x1BD11BDAu;
    x0 += k0; x1 += k1;
#define TF_R(r) do { x0 += x1; x1 = (x1 << (r)) | (x1 >> (32 - (r))); x1 ^= x0; } while (0)
    TF_R(13); TF_R(15); TF_R(26); TF_R(6);
    x0 += k1;  x1 += ks2 + 1u;
    TF_R(17); TF_R(29); TF_R(16); TF_R(24);
    x0 += ks2; x1 += k0 + 2u;
    TF_R(13); TF_R(15); TF_R(26); TF_R(6);
    x0 += k0;  x1 += k1 + 3u;
    TF_R(17); TF_R(29); TF_R(16); TF_R(24);
    x0 += k1;  x1 += ks2 + 4u;
    TF_R(13); TF_R(15); TF_R(26); TF_R(6);
    x0 += ks2; x1 += k0 + 5u;
#undef TF_R
    *o0 = x0; *o1 = x1;
}

__device__ inline float drop_scale(uint32_t fk0, uint32_t fk1, uint32_t idx)
{
    uint32_t o0, o1;
    tf2x32(fk0, fk1, 0u, idx, &o0, &o1);
    uint32_t bits = o0 ^ o1;
    float u = __uint_as_float((bits >> 9) | 0x3f800000u) - 1.0f;
    return (u < 0.9f) ? (1.0f / 0.9f) : 0.0f;
}

// bf16 helpers (round-to-nearest-even)
__device__ inline ushort bf16_rn(float f)
{
    uint32_t u = __float_as_uint(f);
    u += 0x7fffu + ((u >> 16) & 1u);
    return (ushort)(u >> 16);
}
__device__ inline float bf16_f(ushort h) { return __uint_as_float(((uint32_t)h) << 16); }
__device__ inline uint32_t pack2bf(float a, float b)
{
    return (uint32_t)bf16_rn(a) | ((uint32_t)bf16_rn(b) << 16);
}
__device__ inline float bflo(uint32_t u) { return __uint_as_float(u << 16); }
__device__ inline float bfhi(uint32_t u) { return __uint_as_float(u & 0xffff0000u); }

typedef __attribute__((ext_vector_type(8))) short bf16x8;
typedef __attribute__((ext_vector_type(4))) float f32x4;

// ---------------------------------------------------------------------------
// features f32 -> packed bf16x2 (one-time per call, streaming)
// ---------------------------------------------------------------------------
__global__ __launch_bounds__(256) void fcvt_kernel(
    const float4* __restrict__ in, uint2* __restrict__ out, long long n4)
{
    long long stride = (long long)gridDim.x * 256;
    for (long long i = blockIdx.x * 256LL + threadIdx.x; i < n4; i += stride) {
        float4 v = in[i];
        out[i] = make_uint2(pack2bf(v.x, v.y), pack2bf(v.z, v.w));
    }
}

// ---------------------------------------------------------------------------
// prep_all: per type t (8 blocks): convW->swizzled bf16; Wf=convW@fcW ->
// swizzled bf16; bfb = convb@fcW + fcb.
// ---------------------------------------------------------------------------
__global__ __launch_bounds__(256) void prep_all_kernel(
    const float* __restrict__ convW, const float* __restrict__ convb,
    const float* __restrict__ fcW, const float* __restrict__ fcb,
    ushort* __restrict__ WThi, ushort* __restrict__ WTlo,
    ushort* __restrict__ WfThi, ushort* __restrict__ WfTlo,
    float* __restrict__ bfb)
{
    __shared__ float F[128 * 64];
    int t = blockIdx.x, tid = threadIdx.x;
    #pragma unroll
    for (int it = 0; it < 8; ++it) {
        int idx4 = (it * 256 + tid) * 4;
        *(float4*)&F[idx4] = *(const float4*)&fcW[idx4];
    }
    __syncthreads();

    {
        const float* S = convW + (size_t)t * 16384;
        ushort* DH = WThi + (size_t)t * 16384;
        ushort* DL = WTlo + (size_t)t * 16384;
        for (int idx = tid; idx < 16384; idx += 256) {
            int k = idx >> 7, c = idx & 127;
            float v = S[idx];
            ushort hi = bf16_rn(v);
            ushort lo = bf16_rn(v - bf16_f(hi));
            int pos = c * 128 + ((((k >> 3) ^ (c & 15)) << 3) | (k & 7));
            DH[pos] = hi; DL[pos] = lo;
        }
    }

    {
        int r = tid >> 1, cb = (tid & 1) * 32;
        const float* Wrow = convW + (size_t)t * 16384 + (size_t)r * 128;
        float acc[32];
        #pragma unroll
        for (int c = 0; c < 32; ++c) acc[c] = 0.f;
        for (int k = 0; k < 128; ++k) {
            float w = Wrow[k];
            #pragma unroll
            for (int c = 0; c < 32; ++c) acc[c] += w * F[k * 64 + cb + c];
        }
        ushort* FH = WfThi + (size_t)t * 8192;
        ushort* FL = WfTlo + (size_t)t * 8192;
        int swzr = (r & 7);
        #pragma unroll
        for (int c = 0; c < 32; ++c) {
            int col = cb + c;
            float v = acc[c];
            ushort hi = bf16_rn(v);
            ushort lo = bf16_rn(v - bf16_f(hi));
            int pos = col * 128 + ((((r >> 3) ^ (col & 15)) << 3) | swzr);
            FH[pos] = hi; FL[pos] = lo;
        }
    }

    if (tid < 64) {
        float a = fcb[tid];
        const float* bt = convb + (size_t)t * 128;
        for (int k = 0; k < 128; ++k) a += bt[k] * F[k * 64 + tid];
        bfb[(size_t)t * 64 + tid] = a;
    }
}

// ---------------------------------------------------------------------------
// Bucketed CSR build + type bucketing. Bucket = dst>>10.
// hist_all persists per-block LDS hist into cnt[blk][NB] so scatter_all
// skips the redundant re-histogram edge pass.
// ---------------------------------------------------------------------------
#define EPB 4096

__global__ __launch_bounds__(256) void hist_all_kernel(
    const int* __restrict__ d0, const int* __restrict__ d1, const int* __restrict__ d2,
    const int* __restrict__ t1, const int* __restrict__ t2, const int* __restrict__ t3,
    int E0, int E1, int E2, int N1, int N2, int N3,
    int nb0, int nb1, int nb2, int nblk0, int nblk1, int nblk2,
    int cO0, int cO1, int cO2,
    uint32_t* __restrict__ tot, uint32_t* __restrict__ tcnt,
    uint32_t* __restrict__ cnt)
{
    int L = blockIdx.y;
    int tid = threadIdx.x;
    if (L < 3) {
        const int* dst = L == 0 ? d0 : (L == 1 ? d1 : d2);
        int E  = L == 0 ? E0 : (L == 1 ? E1 : E2);
        int NB = L == 0 ? nb0 : (L == 1 ? nb1 : nb2);
        int nblk = L == 0 ? nblk0 : (L == 1 ? nblk1 : nblk2);
        int gO = L == 0 ? 0 : (L == 1 ? nb0 : nb0 + nb1);
        int cO = L == 0 ? cO0 : (L == 1 ? cO1 : cO2);
        if ((int)blockIdx.x >= nblk) return;
        __shared__ uint32_t lh[256];
        lh[tid] = 0;
        __syncthreads();
        int base = blockIdx.x * EPB;
        for (int i = tid; i < EPB; i += 256) {
            int e = base + i;
            if (e < E) atomicAdd(&lh[((uint32_t)dst[e]) >> 10], 1u);
        }
        __syncthreads();
        if (tid < NB) {
            cnt[cO + (size_t)blockIdx.x * NB + tid] = lh[tid];   // persist
            if (lh[tid]) atomicAdd(&tot[gO + tid], lh[tid]);
        }
    } else {
        int totalN = N1 + N2 + N3;
        if ((int)blockIdx.x * 256 >= totalN) return;
        __shared__ uint32_t lh[24];
        if (tid < 24) lh[tid] = 0;
        __syncthreads();
        int i = blockIdx.x * 256 + tid;
        if (i < N1) atomicAdd(&lh[t1[i]], 1u);
        else if (i < N1 + N2) atomicAdd(&lh[8 + t2[i - N1]], 1u);
        else if (i < totalN) atomicAdd(&lh[16 + t3[i - N1 - N2]], 1u);
        __syncthreads();
        if (tid < 24 && lh[tid]) atomicAdd(&tcnt[tid], lh[tid]);
    }
}

__global__ __launch_bounds__(512) void scan_all_kernel(
    const uint32_t* __restrict__ tot, uint32_t* __restrict__ bo,
    uint32_t* __restrict__ bcur, uint32_t* __restrict__ rowptr3,
    const uint32_t* __restrict__ tcnt, int* __restrict__ boff,
    uint32_t* __restrict__ tcur, int* __restrict__ order3,
    int nb0, int nb1, int nb2, int N1, int N2, int N3,
    int r1, int r2, int no1p, int no2p)
{
    __shared__ uint32_t bol[348];
    __shared__ int pB[27];
    __shared__ int cnts[24];
    int t = threadIdx.x;
    int TB = nb0 + nb1 + nb2;
    if (t < 3) {
        int nb = t == 0 ? nb0 : (t == 1 ? nb1 : nb2);
        int g0 = t == 0 ? 0 : (t == 1 ? nb0 : nb0 + nb1);
        int gi0 = g0 + t;
        uint32_t run = 0;
        for (int i = 0; i < nb; ++i) { bol[gi0 + i] = run; run += tot[g0 + i]; }
        bol[gi0 + nb] = run;
        int rp = t == 0 ? 0 : (t == 1 ? r1 : r2);
        int N = t == 0 ? N1 : (t == 1 ? N2 : N3);
        rowptr3[rp + N] = run;
    }
    if (t == 3) {
        for (int L = 0; L < 3; ++L) {
            int a = 0;
            for (int ty = 0; ty < 8; ++ty) {
                pB[L * 9 + ty] = a;
                int c = (int)tcnt[L * 8 + ty];
                cnts[L * 8 + ty] = c;
                tcur[L * 8 + ty] = (uint32_t)a;
                a += (c + 127) & ~127;
            }
            pB[L * 9 + 8] = a;
        }
    }
    __syncthreads();
    for (int i = t; i < TB + 3; i += 512) bo[i] = bol[i];
    if (t < TB) {
        int layer = t < nb0 ? 0 : (t < nb0 + nb1 ? 1 : 2);
        bcur[t] = bol[t + layer];
    }
    if (t < 27) boff[t] = pB[t];
    if (t < 24) {
        int L = t >> 3, ty = t & 7;
        int noff = L == 0 ? 0 : (L == 1 ? no1p : no2p);
        int s = pB[L * 9 + ty] + cnts[t];
        int e2 = pB[L * 9 + ty + 1];
        for (int k = s; k < e2; ++k) order3[noff + k] = -1;
    }
}

// scatter_all: y<3 = edge scatter (hist loaded from cnt) ; y==3 = order3 fill
__global__ __launch_bounds__(256) void scatter_all_kernel(
    const int* __restrict__ s0, const int* __restrict__ d0,
    const int* __restrict__ s1, const int* __restrict__ d1,
    const int* __restrict__ s2, const int* __restrict__ d2,
    const int* __restrict__ t1, const int* __restrict__ t2, const int* __restrict__ t3,
    int E0, int E1, int E2, int N1, int N2, int N3,
    int nb0, int nb1, int nb2, int nblk0, int nblk1, int nblk2,
    int cO0, int cO1, int cO2, const uint32_t* __restrict__ cnt,
    uint32_t* __restrict__ bcur, uint32_t* __restrict__ pairs,
    uint32_t* __restrict__ tcur, int* __restrict__ order3, int no1p, int no2p)
{
    int L = blockIdx.y;
    int tid = threadIdx.x;
    if (L < 3) {
        const int* src = L == 0 ? s0 : (L == 1 ? s1 : s2);
        const int* dst = L == 0 ? d0 : (L == 1 ? d1 : d2);
        int E  = L == 0 ? E0 : (L == 1 ? E1 : E2);
        int NB = L == 0 ? nb0 : (L == 1 ? nb1 : nb2);
        int nblk = L == 0 ? nblk0 : (L == 1 ? nblk1 : nblk2);
        int gO = L == 0 ? 0 : (L == 1 ? nb0 : nb0 + nb1);
        int cO = L == 0 ? cO0 : (L == 1 ? cO1 : cO2);
        uint32_t* pr = pairs + (L == 0 ? 0 : (L == 1 ? E0 : E0 + E1));
        if ((int)blockIdx.x >= nblk) return;

        __shared__ uint32_t lbase[256], rank[256];
        rank[tid] = 0;
        __syncthreads();
        if (tid < NB) {
            uint32_t c = cnt[cO + (size_t)blockIdx.x * NB + tid];
            if (c) lbase[tid] = atomicAdd(&bcur[gO + tid], c);
        }
        __syncthreads();
        int base = blockIdx.x * EPB;
        for (int i = tid; i < EPB; i += 256) {
            int e = base + i;
            if (e < E) {
                uint32_t d = (uint32_t)dst[e];
                uint32_t bk = d >> 10;
                uint32_t r = atomicAdd(&rank[bk], 1u);
                pr[lbase[bk] + r] = ((d & 1023u) << 22) | (uint32_t)src[e];
            }
        }
    } else {
        int totalN = N1 + N2 + N3;
        if ((int)blockIdx.x * 256 >= totalN) return;
        __shared__ uint32_t lh[24], lbase[24];
        if (tid < 24) lh[tid] = 0;
        __syncthreads();
        int i = blockIdx.x * 256 + tid;
        int slot = -1, idx = 0; uint32_t r = 0;
        if (i < N1) { idx = i; slot = t1[idx]; }
        else if (i < N1 + N2) { idx = i - N1; slot = 8 + t2[idx]; }
        else if (i < totalN) { idx = i - N1 - N2; slot = 16 + t3[idx]; }
        if (slot >= 0) r = atomicAdd(&lh[slot], 1u);
        __syncthreads();
        if (tid < 24 && lh[tid]) lbase[tid] = atomicAdd(&tcur[tid], lh[tid]);
        __syncthreads();
        if (slot >= 0) {
            int noff = slot < 8 ? 0 : (slot < 16 ? no1p : no2p);
            order3[noff + lbase[slot] + r] = idx;
        }
    }
}

// bfill: one block per bucket: LDS hist -> scan -> rowptr + fine elist fill
__global__ __launch_bounds__(256) void bfill_kernel(
    const uint32_t* __restrict__ bo, const uint32_t* __restrict__ pairs,
    int* __restrict__ elist3, uint32_t* __restrict__ rowptr3,
    int nb0, int nb1, int nb2, int N1, int N2, int N3,
    int E0, int E1, int r1, int r2)
{
    __shared__ uint32_t hist[1024];
    __shared__ uint32_t cur[1024];
    __shared__ uint32_t psum[256];
    int g = blockIdx.x, tid = threadIdx.x;
    int layer, lb, N, Eoff, rp;
    if (g < nb0) { layer = 0; lb = g; N = N1; Eoff = 0; rp = 0; }
    else if (g < nb0 + nb1) { layer = 1; lb = g - nb0; N = N2; Eoff = E0; rp = r1; }
    else { layer = 2; lb = g - nb0 - nb1; N = N3; Eoff = E0 + E1; rp = r2; }
    uint32_t off = bo[g + layer], end = bo[g + layer + 1];
    int nodeBase = lb << 10;
    int nodesIn = N - nodeBase; if (nodesIn > 1024) nodesIn = 1024;

    #pragma unroll
    for (int i = 0; i < 4; ++i) hist[tid * 4 + i] = 0;
    __syncthreads();
    for (uint32_t e = off + tid; e < end; e += 256)
        atomicAdd(&hist[pairs[Eoff + e] >> 22], 1u);
    __syncthreads();

    uint32_t x[4]; uint32_t s = 0;
    #pragma unroll
    for (int i = 0; i < 4; ++i) { x[i] = hist[tid * 4 + i]; s += x[i]; }
    psum[tid] = s; __syncthreads();
    uint32_t inc = s;
    #pragma unroll
    for (int o = 1; o < 256; o <<= 1) {
        uint32_t y = (tid >= o) ? psum[tid - o] : 0u;
        __syncthreads();
        inc += y; psum[tid] = inc;
        __syncthreads();
    }
    uint32_t run = off + inc - s;
    #pragma unroll
    for (int i = 0; i < 4; ++i) { cur[tid * 4 + i] = run; run += x[i]; }
    __syncthreads();

    for (int i = tid; i < nodesIn; i += 256)
        rowptr3[rp + nodeBase + i] = cur[i];
    __syncthreads();

    for (uint32_t e = off + tid; e < end; e += 256) {
        uint32_t pk = pairs[Eoff + e];
        uint32_t pos = atomicAdd(&cur[pk >> 22], 1u);
        elist3[Eoff + pos] = (int)(pk & 0x3FFFFFu);
    }
}

// ---------------------------------------------------------------------------
// Gather-aggregate (r11 form: VGPR 16, 73% occupancy): 2 nodes per wave,
// fused 8+8-unrolled main loop -> 16 outstanding gathers.
// ---------------------------------------------------------------------------
__global__ __launch_bounds__(256) void aggregate_kernel(
    const uint32_t* __restrict__ hbf, const uint32_t* __restrict__ rowptr,
    const int* __restrict__ elist, uint32_t* __restrict__ agghi,
    uint32_t* __restrict__ agglo, int nout)
{
    int wid = threadIdx.x >> 6, lane = threadIdx.x & 63;
    int n0 = blockIdx.x * 8 + wid * 2;
    if (n0 >= nout) return;
    int n1 = n0 + 1;
    bool v1 = (n1 < nout);
    uint32_t b0 = rowptr[n0], e0 = rowptr[n0 + 1];
    uint32_t b1 = v1 ? rowptr[n1] : 0u, e1 = v1 ? rowptr[n1 + 1] : 0u;
    const uint32_t* base = hbf + lane;
    float a0x = 0.f, a0y = 0.f, a1x = 0.f, a1y = 0.f;
    uint32_t i0 = b0, i1 = b1;

    while (i0 + 8 <= e0 && i1 + 8 <= e1) {
        uint32_t u[8], w[8];
        #pragma unroll
        for (int k = 0; k < 8; ++k) u[k] = base[(size_t)elist[i0 + k] * 64];
        #pragma unroll
        for (int k = 0; k < 8; ++k) w[k] = base[(size_t)elist[i1 + k] * 64];
        #pragma unroll
        for (int k = 0; k < 8; ++k) { a0x += bflo(u[k]); a0y += bfhi(u[k]); }
        #pragma unroll
        for (int k = 0; k < 8; ++k) { a1x += bflo(w[k]); a1y += bfhi(w[k]); }
        i0 += 8; i1 += 8;
    }
    while (i0 + 4 <= e0 && i1 + 4 <= e1) {
        uint32_t u[4], w[4];
        #pragma unroll
        for (int k = 0; k < 4; ++k) u[k] = base[(size_t)elist[i0 + k] * 64];
        #pragma unroll
        for (int k = 0; k < 4; ++k) w[k] = base[(size_t)elist[i1 + k] * 64];
        #pragma unroll
        for (int k = 0; k < 4; ++k) { a0x += bflo(u[k]); a0y += bfhi(u[k]); }
        #pragma unroll
        for (int k = 0; k < 4; ++k) { a1x += bflo(w[k]); a1y += bfhi(w[k]); }
        i0 += 4; i1 += 4;
    }
    while (i0 + 4 <= e0) {
        uint32_t u[4];
        #pragma unroll
        for (int k = 0; k < 4; ++k) u[k] = base[(size_t)elist[i0 + k] * 64];
        #pragma unroll
        for (int k = 0; k < 4; ++k) { a0x += bflo(u[k]); a0y += bfhi(u[k]); }
        i0 += 4;
    }
    while (i1 + 4 <= e1) {
        uint32_t w[4];
        #pragma unroll
        for (int k = 0; k < 4; ++k) w[k] = base[(size_t)elist[i1 + k] * 64];
        #pragma unroll
        for (int k = 0; k < 4; ++k) { a1x += bflo(w[k]); a1y += bfhi(w[k]); }
        i1 += 4;
    }
    for (; i0 < e0; ++i0) {
        uint32_t u = base[(size_t)elist[i0] * 64];
        a0x += bflo(u); a0y += bfhi(u);
    }
    for (; i1 < e1; ++i1) {
        uint32_t w = base[(size_t)elist[i1] * 64];
        a1x += bflo(w); a1y += bfhi(w);
    }

    float sc0 = 1.0f / fmaxf((float)(e0 - b0), 1.0f);
    a0x *= sc0; a0y *= sc0;
    ushort hx = bf16_rn(a0x); ushort lx = bf16_rn(a0x - bf16_f(hx));
    ushort hy = bf16_rn(a0y); ushort ly = bf16_rn(a0y - bf16_f(hy));
    agghi[(size_t)n0 * 64 + lane] = (uint32_t)hx | ((uint32_t)hy << 16);
    agglo[(size_t)n0 * 64 + lane] = (uint32_t)lx | ((uint32_t)ly << 16);
    if (v1) {
        float sc1 = 1.0f / fmaxf((float)(e1 - b1), 1.0f);
        a1x *= sc1; a1y *= sc1;
        ushort hx1 = bf16_rn(a1x); ushort lx1 = bf16_rn(a1x - bf16_f(hx1));
        ushort hy1 = bf16_rn(a1y); ushort ly1 = bf16_rn(a1y - bf16_f(hy1));
        agghi[(size_t)n1 * 64 + lane] = (uint32_t)hx1 | ((uint32_t)hy1 << 16);
        agglo[(size_t)n1 * 64 + lane] = (uint32_t)lx1 | ((uint32_t)ly1 << 16);
    }
}

// ---------------------------------------------------------------------------
// MFMA GEMM (split-bf16): out[n] = [relu](agg[n] @ W[t] + b[t]) [* dropout]
// A fragments direct from global; W staged in LDS (64.5KB, 4 waves/SIMD).
// ---------------------------------------------------------------------------
template<int DOUT, bool RELU, bool DROP, bool OUTBF>
__global__ __launch_bounds__(512) void mfma_gemm_kernel(
    const uint32_t* __restrict__ agghi, const uint32_t* __restrict__ agglo,
    const int* __restrict__ order, const int* __restrict__ off,
    const ushort* __restrict__ WThi, const ushort* __restrict__ WTlo,
    const float* __restrict__ bias8, void* __restrict__ houtv,
    uint32_t fk0, uint32_t fk1)
{
    __shared__ ushort WH[DOUT * 128];
    __shared__ ushort WL[DOUT * 128];
    __shared__ int ND[128];

    int b0 = blockIdx.x * 128;
    if (b0 >= off[8]) return;
    int t = 0;
    #pragma unroll
    for (int u = 1; u < 8; ++u) if (b0 >= off[u]) ++t;
    int tid = threadIdx.x;

    if (tid < 128) ND[tid] = order[b0 + tid];

    {
        const float4* sh = (const float4*)(WThi + (size_t)t * DOUT * 128);
        const float4* sl = (const float4*)(WTlo + (size_t)t * DOUT * 128);
        float4* dh = (float4*)WH; float4* dl = (float4*)WL;
        #pragma unroll
        for (int it = 0; it < DOUT * 16 / 512; ++it) {
            int c = it * 512 + tid;
            dh[c] = sh[c]; dl[c] = sl[c];
        }
    }
    __syncthreads();

    int wid = tid >> 6, lane = tid & 63;
    int r15 = lane & 15, q = lane >> 4;
    int arow = wid * 16 + r15;
    int nd_a = ND[arow];

    const bf16x8* gh = (const bf16x8*)agghi;
    const bf16x8* gl = (const bf16x8*)agglo;
    bf16x8 zero8 = (bf16x8){0, 0, 0, 0, 0, 0, 0, 0};
    bf16x8 ahv[4], alv[4];
    {
        size_t rowb = (size_t)(nd_a < 0 ? 0 : nd_a) * 16;
        #pragma unroll
        for (int ks = 0; ks < 4; ++ks) {
            size_t ix = rowb + (q + ks * 4);
            ahv[ks] = (nd_a >= 0) ? gh[ix] : zero8;
            alv[ks] = (nd_a >= 0) ? gl[ix] : zero8;
        }
    }

    constexpr int NF = DOUT / 16;
    f32x4 acc[NF];
    #pragma unroll
    for (int i = 0; i < NF; ++i) acc[i] = (f32x4){0.f, 0.f, 0.f, 0.f};

    const bf16x8* WHp = (const bf16x8*)WH;
    const bf16x8* WLp = (const bf16x8*)WL;

    #pragma unroll
    for (int ks = 0; ks < 4; ++ks) {
        int sch = (q + ks * 4) ^ r15;
        bf16x8 ah = ahv[ks];
        bf16x8 al = alv[ks];
        #pragma unroll
        for (int nf = 0; nf < NF; ++nf) {
            int col = nf * 16 + r15;
            bf16x8 bh = WHp[col * 16 + sch];
            bf16x8 bl = WLp[col * 16 + sch];
            acc[nf] = __builtin_amdgcn_mfma_f32_16x16x32_bf16(ah, bh, acc[nf], 0, 0, 0);
            acc[nf] = __builtin_amdgcn_mfma_f32_16x16x32_bf16(ah, bl, acc[nf], 0, 0, 0);
            acc[nf] = __builtin_amdgcn_mfma_f32_16x16x32_bf16(al, bh, acc[nf], 0, 0, 0);
        }
    }

    int ndr[4];
    #pragma unroll
    for (int r = 0; r < 4; ++r) ndr[r] = ND[wid * 16 + q * 4 + r];
    const float* bptr = bias8 + (size_t)t * DOUT;

    #pragma unroll
    for (int nf = 0; nf < NF; ++nf) {
        int col = nf * 16 + r15;
        float bv = bptr[col];
        float vr[4];
        #pragma unroll
        for (int r = 0; r < 4; ++r) {
            float v = acc[nf][r] + bv;
            if (RELU) v = fmaxf(v, 0.f);
            if (DROP) {
                int nd = ndr[r] < 0 ? 0 : ndr[r];
                v *= drop_scale(fk0, fk1, (uint32_t)nd * 128u + (uint32_t)col);
            }
            vr[r] = v;
        }
        if (OUTBF) {
            uint32_t* hb = (uint32_t*)houtv;
            #pragma unroll
            for (int r = 0; r < 4; ++r) {
                float w = __shfl_xor(vr[r], 1, 64);
                if ((lane & 1) == 0 && ndr[r] >= 0)
                    hb[(size_t)ndr[r] * (DOUT / 2) + (col >> 1)] = pack2bf(vr[r], w);
            }
        } else {
            float* ho = (float*)houtv;
            #pragma unroll
            for (int r = 0; r < 4; ++r)
                if (ndr[r] >= 0) ho[(size_t)ndr[r] * DOUT + col] = vr[r];
        }
    }
}

// ---------------------------------------------------------------------------
extern "C" void kernel_launch(void* const* d_in, const int* in_sizes, int n_in,
                              void* d_out, int out_size, void* d_ws, size_t ws_size,
                              hipStream_t stream)
{
    const float* features = (const float*)d_in[0];
    const int*   src0 = (const int*)d_in[1];
    const int*   dst0 = (const int*)d_in[2];
    const int*   types1 = (const int*)d_in[3];
    const int*   src1 = (const int*)d_in[4];
    const int*   dst1 = (const int*)d_in[5];
    const int*   types2 = (const int*)d_in[6];
    const int*   src2 = (const int*)d_in[7];
    const int*   dst2 = (const int*)d_in[8];
    const int*   types3 = (const int*)d_in[9];
    const float* convW = (const float*)d_in[10];
    const float* convb = (const float*)d_in[11];
    const float* fcW   = (const float*)d_in[12];
    const float* fcb   = (const float*)d_in[13];

    int N0 = in_sizes[0] / 128;
    int E0 = in_sizes[1], N1 = in_sizes[3];
    int E1 = in_sizes[4], N2 = in_sizes[6];
    int E2 = in_sizes[7], N3 = in_sizes[9];
    int totalN = N1 + N2 + N3;
    int totalE = E0 + E1 + E2;
    int r1 = N1 + 1, r2 = N1 + 1 + N2 + 1;
    int no1p = N1 + 1024, no2p = no1p + N2 + 1024;
    int maxN = N1 > N2 ? N1 : N2; if (N3 > maxN) maxN = N3;

    int nb0 = (N1 + 1023) >> 10, nb1 = (N2 + 1023) >> 10, nb2 = (N3 + 1023) >> 10;
    int TB = nb0 + nb1 + nb2;
    int nblk0 = (E0 + EPB - 1) / EPB, nblk1 = (E1 + EPB - 1) / EPB, nblk2 = (E2 + EPB - 1) / EPB;
    int nblkMax = nblk0 > nblk1 ? nblk0 : nblk1; if (nblk2 > nblkMax) nblkMax = nblk2;
    int nblkT = (totalN + 255) / 256;
    int gx = nblkMax > nblkT ? nblkMax : nblkT;
    int cO0 = 0;
    int cO1 = cO0 + nblk0 * nb0;
    int cO2 = cO1 + nblk1 * nb1;
    int cntEntries = cO2 + nblk2 * nb2;

    char* ws = (char*)d_ws;
    size_t woff = 0;
    auto alloc = [&](size_t bytes) -> void* {
        void* p = ws + woff;
        woff = (woff + bytes + 255) & ~(size_t)255;
        return p;
    };
    uint32_t* fbf     = (uint32_t*)alloc((size_t)N0 * 64 * 4);
    uint32_t* hbf     = fbf;                       // alias: h after L0 agg done
    uint32_t* aggHi   = (uint32_t*)alloc((size_t)maxN * 64 * 4);
    uint32_t* pairs   = aggHi;                     // alias: dead before agg
    uint32_t* aggLo   = (uint32_t*)alloc((size_t)maxN * 64 * 4);
    uint32_t* rowptr3 = (uint32_t*)alloc((size_t)(totalN + 3) * 4);
    int*      elist3  = (int*)alloc((size_t)totalE * 4);
    int*      order3  = (int*)alloc((size_t)(totalN + 3 * 1024) * 4);
    uint32_t* cnt     = (uint32_t*)alloc((size_t)cntEntries * 4);
    uint32_t* tot     = (uint32_t*)alloc((size_t)(TB + 8 + 24) * 4);  // tot | tcnt
    uint32_t* tcnt    = tot + TB + 8;
    uint32_t* bcur    = (uint32_t*)alloc((size_t)(TB + 8) * 4);
    uint32_t* bo      = (uint32_t*)alloc((size_t)(TB + 3) * 4);
    int*      boff    = (int*)alloc(27 * 4);
    uint32_t* tcur    = (uint32_t*)alloc(24 * 4);
    float*    bfb     = (float*)alloc((size_t)8 * 64 * 4);
    ushort*   WThi    = (ushort*)alloc((size_t)8 * 128 * 128 * 2);
    ushort*   WTlo    = (ushort*)alloc((size_t)8 * 128 * 128 * 2);
    ushort*   WfThi   = (ushort*)alloc((size_t)8 * 64 * 128 * 2);
    ushort*   WfTlo   = (ushort*)alloc((size_t)8 * 64 * 128 * 2);
    (void)ws_size; (void)n_in; (void)out_size;

    // --- prep ---
    fcvt_kernel<<<4096, 256, 0, stream>>>(
        (const float4*)features, (uint2*)fbf, (long long)N0 * 32);
    prep_all_kernel<<<8, 256, 0, stream>>>(
        convW, convb, fcW, fcb, WThi, WTlo, WfThi, WfTlo, bfb);

    // --- CSR + type bucketing ---
    hipMemsetAsync(tot, 0, (size_t)(TB + 8 + 24) * 4, stream);
    hist_all_kernel<<<dim3(gx, 4), 256, 0, stream>>>(
        dst0, dst1, dst2, types1, types2, types3,
        E0, E1, E2, N1, N2, N3, nb0, nb1, nb2, nblk0, nblk1, nblk2,
        cO0, cO1, cO2, tot, tcnt, cnt);
    scan_all_kernel<<<1, 512, 0, stream>>>(
        tot, bo, bcur, rowptr3, tcnt, boff, tcur, order3,
        nb0, nb1, nb2, N1, N2, N3, r1, r2, no1p, no2p);
    scatter_all_kernel<<<dim3(gx, 4), 256, 0, stream>>>(
        src0, dst0, src1, dst1, src2, dst2, types1, types2, types3,
        E0, E1, E2, N1, N2, N3, nb0, nb1, nb2, nblk0, nblk1, nblk2,
        cO0, cO1, cO2, cnt, bcur, pairs, tcur, order3, no1p, no2p);
    bfill_kernel<<<TB, 256, 0, stream>>>(bo, pairs, elist3, rowptr3,
        nb0, nb1, nb2, N1, N2, N3, E0, E1, r1, r2);

    // fold-in keys
    uint32_t fk1a, fk1b, fk2a, fk2b;
    tf2x32(0u, 42u, 0u, 1u, &fk1a, &fk1b);
    tf2x32(0u, 42u, 0u, 2u, &fk2a, &fk2b);

    // --- layer 0 ---
    aggregate_kernel<<<(N1 + 7) / 8, 256, 0, stream>>>(
        fbf, rowptr3, elist3, aggHi, aggLo, N1);
    mfma_gemm_kernel<128, true, true, true><<<(N1 + 127) / 128 + 8, 512, 0, stream>>>(
        aggHi, aggLo, order3, boff, WThi, WTlo, convb, hbf, fk1a, fk1b);

    // --- layer 1 ---
    aggregate_kernel<<<(N2 + 7) / 8, 256, 0, stream>>>(
        hbf, rowptr3 + r1, elist3 + E0, aggHi, aggLo, N2);
    mfma_gemm_kernel<128, true, true, true><<<(N2 + 127) / 128 + 8, 512, 0, stream>>>(
        aggHi, aggLo, order3 + no1p, boff + 9, WThi, WTlo, convb, hbf, fk2a, fk2b);

    // --- layer 2 (fc folded, f32 out) ---
    aggregate_kernel<<<(N3 + 7) / 8, 256, 0, stream>>>(
        hbf, rowptr3 + r2, elist3 + E0 + E1, aggHi, aggLo, N3);
    mfma_gemm_kernel<64, false, false, false><<<(N3 + 127) / 128 + 8, 512, 0, stream>>>(
        aggHi, aggLo, order3 + no2p, boff + 18, WfThi, WfTlo, bfb, d_out, 0u, 0u);
}

// Round 14
// 494.051 us; speedup vs baseline: 1.1778x; 1.0900x over previous
//
#include <hip/hip_runtime.h>
#include <cstdint>
#include <cstddef>

// ---------------------------------------------------------------------------
// JAX threefry2x32 (20 rounds). fold_in(key(42), i) = threefry((0,42),(0,i))
// partitionable 32-bit random_bits: bits = o0 ^ o1 (XOR-fold)   [validated r2]
// uniform: u = bitcast((bits>>9)|0x3f800000) - 1.0f ; keep iff u < 0.9f
// ---------------------------------------------------------------------------
__host__ __device__ inline void tf2x32(uint32_t k0, uint32_t k1,
                                       uint32_t x0, uint32_t x1,
                                       uint32_t* o0, uint32_t* o1)
{
    uint32_t ks2 = k0 ^ k1 ^ 0x1BD11BDAu;
    x0 += k0; x1 += k1;
#define TF_R(r) do { x0 += x1; x1 = (x1 << (r)) | (x1 >> (32 - (r))); x1 ^= x0; } while (0)
    TF_R(13); TF_R(15); TF_R(26); TF_R(6);
    x0 += k1;  x1 += ks2 + 1u;
    TF_R(17); TF_R(29); TF_R(16); TF_R(24);
    x0 += ks2; x1 += k0 + 2u;
    TF_R(13); TF_R(15); TF_R(26); TF_R(6);
    x0 += k0;  x1 += k1 + 3u;
    TF_R(17); TF_R(29); TF_R(16); TF_R(24);
    x0 += k1;  x1 += ks2 + 4u;
    TF_R(13); TF_R(15); TF_R(26); TF_R(6);
    x0 += ks2; x1 += k0 + 5u;
#undef TF_R
    *o0 = x0; *o1 = x1;
}

__device__ inline bool drop_keep(uint32_t fk0, uint32_t fk1, uint32_t idx)
{
    uint32_t o0, o1;
    tf2x32(fk0, fk1, 0u, idx, &o0, &o1);
    uint32_t bits = o0 ^ o1;
    float u = __uint_as_float((bits >> 9) | 0x3f800000u) - 1.0f;
    return u < 0.9f;
}

// bf16 helpers (round-to-nearest-even)
__device__ inline ushort bf16_rn(float f)
{
    uint32_t u = __float_as_uint(f);
    u += 0x7fffu + ((u >> 16) & 1u);
    return (ushort)(u >> 16);
}
__device__ inline float bf16_f(ushort h) { return __uint_as_float(((uint32_t)h) << 16); }
__device__ inline uint32_t pack2bf(float a, float b)
{
    return (uint32_t)bf16_rn(a) | ((uint32_t)bf16_rn(b) << 16);
}
__device__ inline float bflo(uint32_t u) { return __uint_as_float(u << 16); }
__device__ inline float bfhi(uint32_t u) { return __uint_as_float(u & 0xffff0000u); }

typedef __attribute__((ext_vector_type(8))) short bf16x8;
typedef __attribute__((ext_vector_type(4))) float f32x4;

#define EPB 4096

// ---------------------------------------------------------------------------
// phase1: fused independent prep work, selected by blockIdx.y:
//   y<3  : per-layer bucket hist -> tot (persist per-block cnt)
//   y==3 : type hist -> tcnt
//   y==4 : fcvt features f32 -> packed bf16x2 (grid-stride)
//   y==5 : prep weights (x<8): convW->swizzled bf16; Wf=convW@fcW; bfb
// ---------------------------------------------------------------------------
__global__ __launch_bounds__(256) void phase1_kernel(
    const float4* __restrict__ fin, uint2* __restrict__ fout, long long n4,
    const float* __restrict__ convW, const float* __restrict__ convb,
    const float* __restrict__ fcW, const float* __restrict__ fcb,
    ushort* __restrict__ WThi, ushort* __restrict__ WTlo,
    ushort* __restrict__ WfThi, ushort* __restrict__ WfTlo,
    float* __restrict__ bfb,
    const int* __restrict__ d0, const int* __restrict__ d1, const int* __restrict__ d2,
    const int* __restrict__ t1, const int* __restrict__ t2, const int* __restrict__ t3,
    int E0, int E1, int E2, int N1, int N2, int N3,
    int nb0, int nb1, int nb2, int nblk0, int nblk1, int nblk2,
    int cO0, int cO1, int cO2,
    uint32_t* __restrict__ tot, uint32_t* __restrict__ tcnt,
    uint32_t* __restrict__ cnt)
{
    __shared__ float F[128 * 64];          // 32KB, reused by all branches
    uint32_t* lh = (uint32_t*)F;
    int L = blockIdx.y;
    int tid = threadIdx.x;

    if (L < 3) {
        const int* dst = L == 0 ? d0 : (L == 1 ? d1 : d2);
        int E  = L == 0 ? E0 : (L == 1 ? E1 : E2);
        int NB = L == 0 ? nb0 : (L == 1 ? nb1 : nb2);
        int nblk = L == 0 ? nblk0 : (L == 1 ? nblk1 : nblk2);
        int gO = L == 0 ? 0 : (L == 1 ? nb0 : nb0 + nb1);
        int cO = L == 0 ? cO0 : (L == 1 ? cO1 : cO2);
        if ((int)blockIdx.x >= nblk) return;
        lh[tid] = 0;
        __syncthreads();
        int base = blockIdx.x * EPB;
        for (int i = tid; i < EPB; i += 256) {
            int e = base + i;
            if (e < E) atomicAdd(&lh[((uint32_t)dst[e]) >> 10], 1u);
        }
        __syncthreads();
        if (tid < NB) {
            cnt[cO + (size_t)blockIdx.x * NB + tid] = lh[tid];
            if (lh[tid]) atomicAdd(&tot[gO + tid], lh[tid]);
        }
    } else if (L == 3) {
        int totalN = N1 + N2 + N3;
        if ((int)blockIdx.x * 256 >= totalN) return;
        if (tid < 24) lh[tid] = 0;
        __syncthreads();
        int i = blockIdx.x * 256 + tid;
        if (i < N1) atomicAdd(&lh[t1[i]], 1u);
        else if (i < N1 + N2) atomicAdd(&lh[8 + t2[i - N1]], 1u);
        else if (i < totalN) atomicAdd(&lh[16 + t3[i - N1 - N2]], 1u);
        __syncthreads();
        if (tid < 24 && lh[tid]) atomicAdd(&tcnt[tid], lh[tid]);
    } else if (L == 4) {
        long long stride = (long long)gridDim.x * 256;
        for (long long i = blockIdx.x * 256LL + tid; i < n4; i += stride) {
            float4 v = fin[i];
            fout[i] = make_uint2(pack2bf(v.x, v.y), pack2bf(v.z, v.w));
        }
    } else {
        if ((int)blockIdx.x >= 8) return;
        int t = blockIdx.x;
        #pragma unroll
        for (int it = 0; it < 8; ++it) {
            int idx4 = (it * 256 + tid) * 4;
            *(float4*)&F[idx4] = *(const float4*)&fcW[idx4];
        }
        __syncthreads();

        {
            const float* S = convW + (size_t)t * 16384;
            ushort* DH = WThi + (size_t)t * 16384;
            ushort* DL = WTlo + (size_t)t * 16384;
            for (int idx = tid; idx < 16384; idx += 256) {
                int k = idx >> 7, c = idx & 127;
                float v = S[idx];
                ushort hi = bf16_rn(v);
                ushort lo = bf16_rn(v - bf16_f(hi));
                int pos = c * 128 + ((((k >> 3) ^ (c & 15)) << 3) | (k & 7));
                DH[pos] = hi; DL[pos] = lo;
            }
        }
        {
            int r = tid >> 1, cb = (tid & 1) * 32;
            const float* Wrow = convW + (size_t)t * 16384 + (size_t)r * 128;
            float acc[32];
            #pragma unroll
            for (int c = 0; c < 32; ++c) acc[c] = 0.f;
            for (int k = 0; k < 128; ++k) {
                float w = Wrow[k];
                #pragma unroll
                for (int c = 0; c < 32; ++c) acc[c] += w * F[k * 64 + cb + c];
            }
            ushort* FH = WfThi + (size_t)t * 8192;
            ushort* FL = WfTlo + (size_t)t * 8192;
            int swzr = (r & 7);
            #pragma unroll
            for (int c = 0; c < 32; ++c) {
                int col = cb + c;
                float v = acc[c];
                ushort hi = bf16_rn(v);
                ushort lo = bf16_rn(v - bf16_f(hi));
                int pos = col * 128 + ((((r >> 3) ^ (col & 15)) << 3) | swzr);
                FH[pos] = hi; FL[pos] = lo;
            }
        }
        if (tid < 64) {
            float a = fcb[tid];
            const float* bt = convb + (size_t)t * 128;
            for (int k = 0; k < 128; ++k) a += bt[k] * F[k * 64 + tid];
            bfb[(size_t)t * 64 + tid] = a;
        }
    }
}

// ---------------------------------------------------------------------------
__global__ __launch_bounds__(512) void scan_all_kernel(
    const uint32_t* __restrict__ tot, uint32_t* __restrict__ bo,
    uint32_t* __restrict__ bcur, uint32_t* __restrict__ rowptr3,
    const uint32_t* __restrict__ tcnt, int* __restrict__ boff,
    uint32_t* __restrict__ tcur, int* __restrict__ order3,
    int nb0, int nb1, int nb2, int N1, int N2, int N3,
    int r1, int r2, int no1p, int no2p)
{
    __shared__ uint32_t bol[348];
    __shared__ int pB[27];
    __shared__ int cnts[24];
    int t = threadIdx.x;
    int TB = nb0 + nb1 + nb2;
    if (t < 3) {
        int nb = t == 0 ? nb0 : (t == 1 ? nb1 : nb2);
        int g0 = t == 0 ? 0 : (t == 1 ? nb0 : nb0 + nb1);
        int gi0 = g0 + t;
        uint32_t run = 0;
        for (int i = 0; i < nb; ++i) { bol[gi0 + i] = run; run += tot[g0 + i]; }
        bol[gi0 + nb] = run;
        int rp = t == 0 ? 0 : (t == 1 ? r1 : r2);
        int N = t == 0 ? N1 : (t == 1 ? N2 : N3);
        rowptr3[rp + N] = run;
    }
    if (t == 3) {
        for (int L = 0; L < 3; ++L) {
            int a = 0;
            for (int ty = 0; ty < 8; ++ty) {
                pB[L * 9 + ty] = a;
                int c = (int)tcnt[L * 8 + ty];
                cnts[L * 8 + ty] = c;
                tcur[L * 8 + ty] = (uint32_t)a;
                a += (c + 127) & ~127;
            }
            pB[L * 9 + 8] = a;
        }
    }
    __syncthreads();
    for (int i = t; i < TB + 3; i += 512) bo[i] = bol[i];
    if (t < TB) {
        int layer = t < nb0 ? 0 : (t < nb0 + nb1 ? 1 : 2);
        bcur[t] = bol[t + layer];
    }
    if (t < 27) boff[t] = pB[t];
    if (t < 24) {
        int L = t >> 3, ty = t & 7;
        int noff = L == 0 ? 0 : (L == 1 ? no1p : no2p);
        int s = pB[L * 9 + ty] + cnts[t];
        int e2 = pB[L * 9 + ty + 1];
        for (int k = s; k < e2; ++k) order3[noff + k] = -1;
    }
}

// scatter_all: y<3 = edge scatter (hist loaded from cnt) ; y==3 = order3 fill
__global__ __launch_bounds__(256) void scatter_all_kernel(
    const int* __restrict__ s0, const int* __restrict__ d0,
    const int* __restrict__ s1, const int* __restrict__ d1,
    const int* __restrict__ s2, const int* __restrict__ d2,
    const int* __restrict__ t1, const int* __restrict__ t2, const int* __restrict__ t3,
    int E0, int E1, int E2, int N1, int N2, int N3,
    int nb0, int nb1, int nb2, int nblk0, int nblk1, int nblk2,
    int cO0, int cO1, int cO2, const uint32_t* __restrict__ cnt,
    uint32_t* __restrict__ bcur, uint32_t* __restrict__ pairs,
    uint32_t* __restrict__ tcur, int* __restrict__ order3, int no1p, int no2p)
{
    int L = blockIdx.y;
    int tid = threadIdx.x;
    if (L < 3) {
        const int* src = L == 0 ? s0 : (L == 1 ? s1 : s2);
        const int* dst = L == 0 ? d0 : (L == 1 ? d1 : d2);
        int E  = L == 0 ? E0 : (L == 1 ? E1 : E2);
        int NB = L == 0 ? nb0 : (L == 1 ? nb1 : nb2);
        int nblk = L == 0 ? nblk0 : (L == 1 ? nblk1 : nblk2);
        int gO = L == 0 ? 0 : (L == 1 ? nb0 : nb0 + nb1);
        int cO = L == 0 ? cO0 : (L == 1 ? cO1 : cO2);
        uint32_t* pr = pairs + (L == 0 ? 0 : (L == 1 ? E0 : E0 + E1));
        if ((int)blockIdx.x >= nblk) return;

        __shared__ uint32_t lbase[256], rank[256];
        rank[tid] = 0;
        __syncthreads();
        if (tid < NB) {
            uint32_t c = cnt[cO + (size_t)blockIdx.x * NB + tid];
            if (c) lbase[tid] = atomicAdd(&bcur[gO + tid], c);
        }
        __syncthreads();
        int base = blockIdx.x * EPB;
        for (int i = tid; i < EPB; i += 256) {
            int e = base + i;
            if (e < E) {
                uint32_t d = (uint32_t)dst[e];
                uint32_t bk = d >> 10;
                uint32_t r = atomicAdd(&rank[bk], 1u);
                pr[lbase[bk] + r] = ((d & 1023u) << 22) | (uint32_t)src[e];
            }
        }
    } else {
        int totalN = N1 + N2 + N3;
        if ((int)blockIdx.x * 256 >= totalN) return;
        __shared__ uint32_t lh[24], lbase[24];
        if (tid < 24) lh[tid] = 0;
        __syncthreads();
        int i = blockIdx.x * 256 + tid;
        int slot = -1, idx = 0; uint32_t r = 0;
        if (i < N1) { idx = i; slot = t1[idx]; }
        else if (i < N1 + N2) { idx = i - N1; slot = 8 + t2[idx]; }
        else if (i < totalN) { idx = i - N1 - N2; slot = 16 + t3[idx]; }
        if (slot >= 0) r = atomicAdd(&lh[slot], 1u);
        __syncthreads();
        if (tid < 24 && lh[tid]) lbase[tid] = atomicAdd(&tcur[tid], lh[tid]);
        __syncthreads();
        if (slot >= 0) {
            int noff = slot < 8 ? 0 : (slot < 16 ? no1p : no2p);
            order3[noff + lbase[slot] + r] = idx;
        }
    }
}

// bfill: one block per bucket: LDS hist -> scan -> rowptr + fine elist fill
__global__ __launch_bounds__(256) void bfill_kernel(
    const uint32_t* __restrict__ bo, const uint32_t* __restrict__ pairs,
    int* __restrict__ elist3, uint32_t* __restrict__ rowptr3,
    int nb0, int nb1, int nb2, int N1, int N2, int N3,
    int E0, int E1, int r1, int r2)
{
    __shared__ uint32_t hist[1024];
    __shared__ uint32_t cur[1024];
    __shared__ uint32_t psum[256];
    int g = blockIdx.x, tid = threadIdx.x;
    int layer, lb, N, Eoff, rp;
    if (g < nb0) { layer = 0; lb = g; N = N1; Eoff = 0; rp = 0; }
    else if (g < nb0 + nb1) { layer = 1; lb = g - nb0; N = N2; Eoff = E0; rp = r1; }
    else { layer = 2; lb = g - nb0 - nb1; N = N3; Eoff = E0 + E1; rp = r2; }
    uint32_t off = bo[g + layer], end = bo[g + layer + 1];
    int nodeBase = lb << 10;
    int nodesIn = N - nodeBase; if (nodesIn > 1024) nodesIn = 1024;

    #pragma unroll
    for (int i = 0; i < 4; ++i) hist[tid * 4 + i] = 0;
    __syncthreads();
    for (uint32_t e = off + tid; e < end; e += 256)
        atomicAdd(&hist[pairs[Eoff + e] >> 22], 1u);
    __syncthreads();

    uint32_t x[4]; uint32_t s = 0;
    #pragma unroll
    for (int i = 0; i < 4; ++i) { x[i] = hist[tid * 4 + i]; s += x[i]; }
    psum[tid] = s; __syncthreads();
    uint32_t inc = s;
    #pragma unroll
    for (int o = 1; o < 256; o <<= 1) {
        uint32_t y = (tid >= o) ? psum[tid - o] : 0u;
        __syncthreads();
        inc += y; psum[tid] = inc;
        __syncthreads();
    }
    uint32_t run = off + inc - s;
    #pragma unroll
    for (int i = 0; i < 4; ++i) { cur[tid * 4 + i] = run; run += x[i]; }
    __syncthreads();

    for (int i = tid; i < nodesIn; i += 256)
        rowptr3[rp + nodeBase + i] = cur[i];
    __syncthreads();

    for (uint32_t e = off + tid; e < end; e += 256) {
        uint32_t pk = pairs[Eoff + e];
        uint32_t pos = atomicAdd(&cur[pk >> 22], 1u);
        elist3[Eoff + pos] = (int)(pk & 0x3FFFFFu);
    }
}

// ---------------------------------------------------------------------------
// Gather-aggregate (r11 form, VGPR-lean) + fused dropout-mask generation:
// the keep-bits depend only on node index, and this kernel is memory-bound
// (VALU 31%) -> threefry rides free. 4 threefry/lane + 4 ballots per 2 nodes.
// ---------------------------------------------------------------------------
__global__ __launch_bounds__(256) void aggregate_kernel(
    const uint32_t* __restrict__ hbf, const uint32_t* __restrict__ rowptr,
    const int* __restrict__ elist, uint32_t* __restrict__ agghi,
    uint32_t* __restrict__ agglo, uint32_t* __restrict__ maskbuf,
    uint32_t fk0, uint32_t fk1, int do_drop, int nout)
{
    int wid = threadIdx.x >> 6, lane = threadIdx.x & 63;
    int n0 = blockIdx.x * 8 + wid * 2;
    if (n0 >= nout) return;
    int n1 = n0 + 1;
    bool v1 = (n1 < nout);
    uint32_t b0 = rowptr[n0], e0 = rowptr[n0 + 1];
    uint32_t b1 = v1 ? rowptr[n1] : 0u, e1 = v1 ? rowptr[n1 + 1] : 0u;
    const uint32_t* base = hbf + lane;
    float a0x = 0.f, a0y = 0.f, a1x = 0.f, a1y = 0.f;
    uint32_t i0 = b0, i1 = b1;

    while (i0 + 8 <= e0 && i1 + 8 <= e1) {
        uint32_t u[8], w[8];
        #pragma unroll
        for (int k = 0; k < 8; ++k) u[k] = base[(size_t)elist[i0 + k] * 64];
        #pragma unroll
        for (int k = 0; k < 8; ++k) w[k] = base[(size_t)elist[i1 + k] * 64];
        #pragma unroll
        for (int k = 0; k < 8; ++k) { a0x += bflo(u[k]); a0y += bfhi(u[k]); }
        #pragma unroll
        for (int k = 0; k < 8; ++k) { a1x += bflo(w[k]); a1y += bfhi(w[k]); }
        i0 += 8; i1 += 8;
    }
    while (i0 + 4 <= e0 && i1 + 4 <= e1) {
        uint32_t u[4], w[4];
        #pragma unroll
        for (int k = 0; k < 4; ++k) u[k] = base[(size_t)elist[i0 + k] * 64];
        #pragma unroll
        for (int k = 0; k < 4; ++k) w[k] = base[(size_t)elist[i1 + k] * 64];
        #pragma unroll
        for (int k = 0; k < 4; ++k) { a0x += bflo(u[k]); a0y += bfhi(u[k]); }
        #pragma unroll
        for (int k = 0; k < 4; ++k) { a1x += bflo(w[k]); a1y += bfhi(w[k]); }
        i0 += 4; i1 += 4;
    }
    while (i0 + 4 <= e0) {
        uint32_t u[4];
        #pragma unroll
        for (int k = 0; k < 4; ++k) u[k] = base[(size_t)elist[i0 + k] * 64];
        #pragma unroll
        for (int k = 0; k < 4; ++k) { a0x += bflo(u[k]); a0y += bfhi(u[k]); }
        i0 += 4;
    }
    while (i1 + 4 <= e1) {
        uint32_t w[4];
        #pragma unroll
        for (int k = 0; k < 4; ++k) w[k] = base[(size_t)elist[i1 + k] * 64];
        #pragma unroll
        for (int k = 0; k < 4; ++k) { a1x += bflo(w[k]); a1y += bfhi(w[k]); }
        i1 += 4;
    }
    for (; i0 < e0; ++i0) {
        uint32_t u = base[(size_t)elist[i0] * 64];
        a0x += bflo(u); a0y += bfhi(u);
    }
    for (; i1 < e1; ++i1) {
        uint32_t w = base[(size_t)elist[i1] * 64];
        a1x += bflo(w); a1y += bfhi(w);
    }

    float sc0 = 1.0f / fmaxf((float)(e0 - b0), 1.0f);
    a0x *= sc0; a0y *= sc0;
    ushort hx = bf16_rn(a0x); ushort lx = bf16_rn(a0x - bf16_f(hx));
    ushort hy = bf16_rn(a0y); ushort ly = bf16_rn(a0y - bf16_f(hy));
    agghi[(size_t)n0 * 64 + lane] = (uint32_t)hx | ((uint32_t)hy << 16);
    agglo[(size_t)n0 * 64 + lane] = (uint32_t)lx | ((uint32_t)ly << 16);
    if (v1) {
        float sc1 = 1.0f / fmaxf((float)(e1 - b1), 1.0f);
        a1x *= sc1; a1y *= sc1;
        ushort hx1 = bf16_rn(a1x); ushort lx1 = bf16_rn(a1x - bf16_f(hx1));
        ushort hy1 = bf16_rn(a1y); ushort ly1 = bf16_rn(a1y - bf16_f(hy1));
        agghi[(size_t)n1 * 64 + lane] = (uint32_t)hx1 | ((uint32_t)hy1 << 16);
        agglo[(size_t)n1 * 64 + lane] = (uint32_t)lx1 | ((uint32_t)ly1 << 16);
    }

    // dropout mask for this layer's output rows (wave-uniform control flow)
    if (do_drop) {
        unsigned long long mA = __ballot(drop_keep(fk0, fk1, (uint32_t)n0 * 128u + lane));
        unsigned long long mB = __ballot(drop_keep(fk0, fk1, (uint32_t)n0 * 128u + 64u + lane));
        if (lane == 0)
            *(uint4*)&maskbuf[(size_t)n0 * 4] = make_uint4(
                (uint32_t)mA, (uint32_t)(mA >> 32), (uint32_t)mB, (uint32_t)(mB >> 32));
        if (v1) {
            unsigned long long mC = __ballot(drop_keep(fk0, fk1, (uint32_t)n1 * 128u + lane));
            unsigned long long mD = __ballot(drop_keep(fk0, fk1, (uint32_t)n1 * 128u + 64u + lane));
            if (lane == 0)
                *(uint4*)&maskbuf[(size_t)n1 * 4] = make_uint4(
                    (uint32_t)mC, (uint32_t)(mC >> 32), (uint32_t)mD, (uint32_t)(mD >> 32));
        }
    }
}

// ---------------------------------------------------------------------------
// MFMA GEMM (split-bf16): out[n] = [relu](agg[n] @ W[t] + b[t]) [* dropout]
// A direct from global; W in LDS (64.5KB, 4 waves/SIMD). Dropout consumes
// precomputed mask bits (4 uint4 loads) instead of 32 threefry calls.
// ---------------------------------------------------------------------------
template<int DOUT, bool RELU, bool DROP, bool OUTBF>
__global__ __launch_bounds__(512) void mfma_gemm_kernel(
    const uint32_t* __restrict__ agghi, const uint32_t* __restrict__ agglo,
    const int* __restrict__ order, const int* __restrict__ off,
    const ushort* __restrict__ WThi, const ushort* __restrict__ WTlo,
    const float* __restrict__ bias8, void* __restrict__ houtv,
    const uint32_t* __restrict__ maskbuf)
{
    __shared__ ushort WH[DOUT * 128];
    __shared__ ushort WL[DOUT * 128];
    __shared__ int ND[128];

    int b0 = blockIdx.x * 128;
    if (b0 >= off[8]) return;
    int t = 0;
    #pragma unroll
    for (int u = 1; u < 8; ++u) if (b0 >= off[u]) ++t;
    int tid = threadIdx.x;

    if (tid < 128) ND[tid] = order[b0 + tid];

    {
        const float4* sh = (const float4*)(WThi + (size_t)t * DOUT * 128);
        const float4* sl = (const float4*)(WTlo + (size_t)t * DOUT * 128);
        float4* dh = (float4*)WH; float4* dl = (float4*)WL;
        #pragma unroll
        for (int it = 0; it < DOUT * 16 / 512; ++it) {
            int c = it * 512 + tid;
            dh[c] = sh[c]; dl[c] = sl[c];
        }
    }
    __syncthreads();

    int wid = tid >> 6, lane = tid & 63;
    int r15 = lane & 15, q = lane >> 4;
    int arow = wid * 16 + r15;
    int nd_a = ND[arow];

    const bf16x8* gh = (const bf16x8*)agghi;
    const bf16x8* gl = (const bf16x8*)agglo;
    bf16x8 zero8 = (bf16x8){0, 0, 0, 0, 0, 0, 0, 0};
    bf16x8 ahv[4], alv[4];
    {
        size_t rowb = (size_t)(nd_a < 0 ? 0 : nd_a) * 16;
        #pragma unroll
        for (int ks = 0; ks < 4; ++ks) {
            size_t ix = rowb + (q + ks * 4);
            ahv[ks] = (nd_a >= 0) ? gh[ix] : zero8;
            alv[ks] = (nd_a >= 0) ? gl[ix] : zero8;
        }
    }

    constexpr int NF = DOUT / 16;
    f32x4 acc[NF];
    #pragma unroll
    for (int i = 0; i < NF; ++i) acc[i] = (f32x4){0.f, 0.f, 0.f, 0.f};

    const bf16x8* WHp = (const bf16x8*)WH;
    const bf16x8* WLp = (const bf16x8*)WL;

    #pragma unroll
    for (int ks = 0; ks < 4; ++ks) {
        int sch = (q + ks * 4) ^ r15;
        bf16x8 ah = ahv[ks];
        bf16x8 al = alv[ks];
        #pragma unroll
        for (int nf = 0; nf < NF; ++nf) {
            int col = nf * 16 + r15;
            bf16x8 bh = WHp[col * 16 + sch];
            bf16x8 bl = WLp[col * 16 + sch];
            acc[nf] = __builtin_amdgcn_mfma_f32_16x16x32_bf16(ah, bh, acc[nf], 0, 0, 0);
            acc[nf] = __builtin_amdgcn_mfma_f32_16x16x32_bf16(ah, bl, acc[nf], 0, 0, 0);
            acc[nf] = __builtin_amdgcn_mfma_f32_16x16x32_bf16(al, bh, acc[nf], 0, 0, 0);
        }
    }

    int ndr[4];
    #pragma unroll
    for (int r = 0; r < 4; ++r) ndr[r] = ND[wid * 16 + q * 4 + r];
    uint4 mrow[4];
    if (DROP) {
        #pragma unroll
        for (int r = 0; r < 4; ++r) {
            int nd = ndr[r] < 0 ? 0 : ndr[r];
            mrow[r] = *(const uint4*)&maskbuf[(size_t)nd * 4];
        }
    }
    const float* bptr = bias8 + (size_t)t * DOUT;

    #pragma unroll
    for (int nf = 0; nf < NF; ++nf) {
        int col = nf * 16 + r15;
        float bv = bptr[col];
        float vr[4];
        #pragma unroll
        for (int r = 0; r < 4; ++r) {
            float v = acc[nf][r] + bv;
            if (RELU) v = fmaxf(v, 0.f);
            if (DROP) {
                const uint32_t* mw = (const uint32_t*)&mrow[r];
                uint32_t m = mw[nf >> 1];               // col>>5 == nf>>1 (compile-time)
                v = ((m >> (col & 31)) & 1u) ? v * (1.0f / 0.9f) : 0.0f;
            }
            vr[r] = v;
        }
        if (OUTBF) {
            uint32_t* hb = (uint32_t*)houtv;
            #pragma unroll
            for (int r = 0; r < 4; ++r) {
                float w = __shfl_xor(vr[r], 1, 64);
                if ((lane & 1) == 0 && ndr[r] >= 0)
                    hb[(size_t)ndr[r] * (DOUT / 2) + (col >> 1)] = pack2bf(vr[r], w);
            }
        } else {
            float* ho = (float*)houtv;
            #pragma unroll
            for (int r = 0; r < 4; ++r)
                if (ndr[r] >= 0) ho[(size_t)ndr[r] * DOUT + col] = vr[r];
        }
    }
}

// ---------------------------------------------------------------------------
extern "C" void kernel_launch(void* const* d_in, const int* in_sizes, int n_in,
                              void* d_out, int out_size, void* d_ws, size_t ws_size,
                              hipStream_t stream)
{
    const float* features = (const float*)d_in[0];
    const int*   src0 = (const int*)d_in[1];
    const int*   dst0 = (const int*)d_in[2];
    const int*   types1 = (const int*)d_in[3];
    const int*   src1 = (const int*)d_in[4];
    const int*   dst1 = (const int*)d_in[5];
    const int*   types2 = (const int*)d_in[6];
    const int*   src2 = (const int*)d_in[7];
    const int*   dst2 = (const int*)d_in[8];
    const int*   types3 = (const int*)d_in[9];
    const float* convW = (const float*)d_in[10];
    const float* convb = (const float*)d_in[11];
    const float* fcW   = (const float*)d_in[12];
    const float* fcb   = (const float*)d_in[13];

    int N0 = in_sizes[0] / 128;
    int E0 = in_sizes[1], N1 = in_sizes[3];
    int E1 = in_sizes[4], N2 = in_sizes[6];
    int E2 = in_sizes[7], N3 = in_sizes[9];
    int totalN = N1 + N2 + N3;
    int totalE = E0 + E1 + E2;
    int r1 = N1 + 1, r2 = N1 + 1 + N2 + 1;
    int no1p = N1 + 1024, no2p = no1p + N2 + 1024;
    int maxN = N1 > N2 ? N1 : N2; if (N3 > maxN) maxN = N3;

    int nb0 = (N1 + 1023) >> 10, nb1 = (N2 + 1023) >> 10, nb2 = (N3 + 1023) >> 10;
    int TB = nb0 + nb1 + nb2;
    int nblk0 = (E0 + EPB - 1) / EPB, nblk1 = (E1 + EPB - 1) / EPB, nblk2 = (E2 + EPB - 1) / EPB;
    int nblkMax = nblk0 > nblk1 ? nblk0 : nblk1; if (nblk2 > nblkMax) nblkMax = nblk2;
    int nblkT = (totalN + 255) / 256;
    int gx = nblkMax > nblkT ? nblkMax : nblkT;
    int gxF = gx > 1024 ? gx : 1024;     // phase1 needs blocks for fcvt BW
    int cO0 = 0;
    int cO1 = cO0 + nblk0 * nb0;
    int cO2 = cO1 + nblk1 * nb1;
    int cntEntries = cO2 + nblk2 * nb2;

    char* ws = (char*)d_ws;
    size_t woff = 0;
    auto alloc = [&](size_t bytes) -> void* {
        void* p = ws + woff;
        woff = (woff + bytes + 255) & ~(size_t)255;
        return p;
    };
    uint32_t* fbf     = (uint32_t*)alloc((size_t)N0 * 64 * 4);
    uint32_t* hbf     = fbf;                       // alias: h after L0 agg done
    uint32_t* aggHi   = (uint32_t*)alloc((size_t)maxN * 64 * 4);
    uint32_t* pairs   = aggHi;                     // alias: dead before agg
    uint32_t* aggLo   = (uint32_t*)alloc((size_t)maxN * 64 * 4);
    uint32_t* maskbuf = (uint32_t*)alloc((size_t)maxN * 4 * 4);
    uint32_t* rowptr3 = (uint32_t*)alloc((size_t)(totalN + 3) * 4);
    int*      elist3  = (int*)alloc((size_t)totalE * 4);
    int*      order3  = (int*)alloc((size_t)(totalN + 3 * 1024) * 4);
    uint32_t* cnt     = (uint32_t*)alloc((size_t)cntEntries * 4);
    uint32_t* tot     = (uint32_t*)alloc((size_t)(TB + 8 + 24) * 4);  // tot | tcnt
    uint32_t* tcnt    = tot + TB + 8;
    uint32_t* bcur    = (uint32_t*)alloc((size_t)(TB + 8) * 4);
    uint32_t* bo      = (uint32_t*)alloc((size_t)(TB + 3) * 4);
    int*      boff    = (int*)alloc(27 * 4);
    uint32_t* tcur    = (uint32_t*)alloc(24 * 4);
    float*    bfb     = (float*)alloc((size_t)8 * 64 * 4);
    ushort*   WThi    = (ushort*)alloc((size_t)8 * 128 * 128 * 2);
    ushort*   WTlo    = (ushort*)alloc((size_t)8 * 128 * 128 * 2);
    ushort*   WfThi   = (ushort*)alloc((size_t)8 * 64 * 128 * 2);
    ushort*   WfTlo   = (ushort*)alloc((size_t)8 * 64 * 128 * 2);
    (void)ws_size; (void)n_in; (void)out_size;

    // --- phase1: fcvt + weight prep + all histograms, one dispatch ---
    hipMemsetAsync(tot, 0, (size_t)(TB + 8 + 24) * 4, stream);
    phase1_kernel<<<dim3(gxF, 6), 256, 0, stream>>>(
        (const float4*)features, (uint2*)fbf, (long long)N0 * 32,
        convW, convb, fcW, fcb, WThi, WTlo, WfThi, WfTlo, bfb,
        dst0, dst1, dst2, types1, types2, types3,
        E0, E1, E2, N1, N2, N3, nb0, nb1, nb2, nblk0, nblk1, nblk2,
        cO0, cO1, cO2, tot, tcnt, cnt);
    scan_all_kernel<<<1, 512, 0, stream>>>(
        tot, bo, bcur, rowptr3, tcnt, boff, tcur, order3,
        nb0, nb1, nb2, N1, N2, N3, r1, r2, no1p, no2p);
    scatter_all_kernel<<<dim3(gx, 4), 256, 0, stream>>>(
        src0, dst0, src1, dst1, src2, dst2, types1, types2, types3,
        E0, E1, E2, N1, N2, N3, nb0, nb1, nb2, nblk0, nblk1, nblk2,
        cO0, cO1, cO2, cnt, bcur, pairs, tcur, order3, no1p, no2p);
    bfill_kernel<<<TB, 256, 0, stream>>>(bo, pairs, elist3, rowptr3,
        nb0, nb1, nb2, N1, N2, N3, E0, E1, r1, r2);

    // fold-in keys
    uint32_t fk1a, fk1b, fk2a, fk2b;
    tf2x32(0u, 42u, 0u, 1u, &fk1a, &fk1b);
    tf2x32(0u, 42u, 0u, 2u, &fk2a, &fk2b);

    // --- layer 0 ---
    aggregate_kernel<<<(N1 + 7) / 8, 256, 0, stream>>>(
        fbf, rowptr3, elist3, aggHi, aggLo, maskbuf, fk1a, fk1b, 1, N1);
    mfma_gemm_kernel<128, true, true, true><<<(N1 + 127) / 128 + 8, 512, 0, stream>>>(
        aggHi, aggLo, order3, boff, WThi, WTlo, convb, hbf, maskbuf);

    // --- layer 1 ---
    aggregate_kernel<<<(N2 + 7) / 8, 256, 0, stream>>>(
        hbf, rowptr3 + r1, elist3 + E0, aggHi, aggLo, maskbuf, fk2a, fk2b, 1, N2);
    mfma_gemm_kernel<128, true, true, true><<<(N2 + 127) / 128 + 8, 512, 0, stream>>>(
        aggHi, aggLo, order3 + no1p, boff + 9, WThi, WTlo, convb, hbf, maskbuf);

    // --- layer 2 (fc folded, f32 out) ---
    aggregate_kernel<<<(N3 + 7) / 8, 256, 0, stream>>>(
        hbf, rowptr3 + r2, elist3 + E0 + E1, aggHi, aggLo, maskbuf, 0u, 0u, 0, N3);
    mfma_gemm_kernel<64, false, false, false><<<(N3 + 127) / 128 + 8, 512, 0, stream>>>(
        aggHi, aggLo, order3 + no2p, boff + 18, WfThi, WfTlo, bfb, d_out, nullptr);
}